// Round 11
// baseline (243.042 us; speedup 1.0000x reference)
//
#include <hip/hip_runtime.h>
#include <hip/hip_fp16.h>
#include <math.h>

// SGC 2-layer: out = A_hat * elu(A_hat * X * W1 + b1) * W2 + b2
// A_hat = D^-1/2 A D^-1/2 (in-degree based, clip(deg,1))
// R2: CSR build + gather aggregation (no float atomics).
// R4: CSR via two-level counting sort. 510->348us.
// R5: fp16 gather operands. 348->312us.
// R6: wide gather loads + degree-perm + packed CSR. 312->308us.
// R7: MFMA fp16 fused matmul (h stays in LDS). 308->239us; gather1 62.5us.
// R9/R10: perm fused into pass2 -> gather1 REGRESSED 62.5->74us (reproducible;
//     NT-store revert in R10 did NOT recover it -> perm content is the suspect).
// R11: restore R7-exact pass2 + standalone perm_build (4096-chunk degree sort);
//     keep gather2 12-node/wave 5-lane grouping + NT `out` stores.

#define DIN  128
#define DHID 128
#define DOUT 40
#define BSHIFT 9
#define BNODES 512   // 1 << BSHIFT

union U8  { uint2 u; __half2 h[2]; };
union U16 { uint4 u; __half2 h[4]; };

typedef _Float16     f16x8 __attribute__((ext_vector_type(8)));
typedef float        f32x4 __attribute__((ext_vector_type(4)));
typedef unsigned int u32x4 __attribute__((ext_vector_type(4)));
union F16X8 { uint4 u; f16x8 f; };
union HCV   { __half h; unsigned short s; };
union FV4   { float4 h; f32x4 v; };

__device__ __forceinline__ float elu_f(float x) {
    return x > 0.0f ? x : (expf(x) - 1.0f);
}

// ---------------- CSR build (two-level counting sort, packed records) ----------------

__global__ void pass1_bucket(const int* __restrict__ src, const int* __restrict__ dst,
                             int E, int NB, int cap,
                             int* __restrict__ bcur, int* __restrict__ bbuf) {
    __shared__ int cnt[256];
    __shared__ int wcur[256];
    const int CHUNK = 8192;
    for (long base = (long)blockIdx.x * CHUNK; base < E; base += (long)gridDim.x * CHUNK) {
        int n = min(CHUNK, (int)(E - base));
        if (threadIdx.x < 256) cnt[threadIdx.x] = 0;
        __syncthreads();
        for (int i = threadIdx.x; i < n; i += blockDim.x) {
            int b = dst[base + i] >> BSHIFT;
            atomicAdd(&cnt[b], 1);
        }
        __syncthreads();
        if (threadIdx.x < NB) {
            int c = cnt[threadIdx.x];
            wcur[threadIdx.x] = (c > 0) ? atomicAdd(&bcur[threadIdx.x], c) : 0;
        }
        __syncthreads();
        for (int i = threadIdx.x; i < n; i += blockDim.x) {
            int s = src[base + i];
            int d = dst[base + i];
            int b = d >> BSHIFT;
            int slot = atomicAdd(&wcur[b], 1);
            if (slot < cap) bbuf[(long)b * cap + slot] = (s << BSHIFT) | (d & (BNODES - 1));
        }
        __syncthreads();
    }
}

__global__ void bucket_scan(const int* __restrict__ bcur, int* __restrict__ bbase, int NB) {
    if (blockIdx.x == 0 && threadIdx.x == 0) {
        int run = 0;
        for (int b = 0; b < NB; ++b) { bbase[b] = run; run += bcur[b]; }
        bbase[NB] = run;
    }
}

// per-bucket LDS counting sort -> norm, rowptr, esrc (R7-exact)
__global__ void pass2_sort(const int* __restrict__ bbuf, const int* __restrict__ bcur,
                           const int* __restrict__ bbase, int N, int NB, int cap,
                           float* __restrict__ norm, int* __restrict__ rowptr,
                           int* __restrict__ esrc) {
    __shared__ int cnt[BNODES];
    int b = blockIdx.x;
    int n_b = min(bcur[b], cap);
    int gbase = bbase[b];
    int dbase = b << BSHIFT;
    const int* eb = bbuf + (long)b * cap;
    for (int i = threadIdx.x; i < BNODES; i += blockDim.x) cnt[i] = 0;
    __syncthreads();
    for (int i = threadIdx.x; i < n_b; i += blockDim.x)
        atomicAdd(&cnt[eb[i] & (BNODES - 1)], 1);
    __syncthreads();
    for (int i = threadIdx.x; i < BNODES; i += blockDim.x) {
        int d = dbase + i;
        if (d < N) norm[d] = rsqrtf(fmaxf((float)cnt[i], 1.0f));
    }
    __syncthreads();
    if (threadIdx.x == 0) {
        int run = 0;
        #pragma unroll 4
        for (int i = 0; i < BNODES; ++i) { int c = cnt[i]; cnt[i] = run; run += c; }
    }
    __syncthreads();
    for (int i = threadIdx.x; i < BNODES; i += blockDim.x) {
        int d = dbase + i;
        if (d < N) rowptr[d] = gbase + cnt[i];
    }
    if (b == NB - 1 && threadIdx.x == 0) rowptr[N] = bbase[NB];
    __syncthreads();
    for (int i = threadIdx.x; i < n_b; i += blockDim.x) {
        int v = eb[i];
        int slot = atomicAdd(&cnt[v & (BNODES - 1)], 1);
        esrc[gbase + slot] = ((unsigned)v) >> BSHIFT;
    }
}

// chunk-local degree sort (R7-exact): perm[base..base+n) = chunk nodes by degree.
__global__ void perm_build(const int* __restrict__ rowptr, int* __restrict__ perm, int N) {
    __shared__ int lcnt[1024];
    __shared__ int lbase[1024];
    const int CHUNK = 4096;
    for (long base = (long)blockIdx.x * CHUNK; base < N; base += (long)gridDim.x * CHUNK) {
        int n = min(CHUNK, (int)(N - base));
        for (int i = threadIdx.x; i < 1024; i += 256) lcnt[i] = 0;
        __syncthreads();
        for (int i = threadIdx.x; i < n; i += 256) {
            int d = min(rowptr[base + i + 1] - rowptr[base + i], 1023);
            atomicAdd(&lcnt[d], 1);
        }
        __syncthreads();
        if (threadIdx.x == 0) {
            int run = 0;
            for (int i = 0; i < 1024; ++i) { int c = lcnt[i]; lbase[i] = run; run += c; }
        }
        __syncthreads();
        for (int i = threadIdx.x; i < 1024; i += 256) lcnt[i] = 0;
        __syncthreads();
        for (int i = threadIdx.x; i < n; i += 256) {
            int d = min(rowptr[base + i + 1] - rowptr[base + i], 1023);
            int pos = lbase[d] + atomicAdd(&lcnt[d], 1);
            perm[base + pos] = base + (int)i;
        }
        __syncthreads();
    }
}

__global__ void norm_from_deg(const int* __restrict__ deg, float* __restrict__ norm, int N) {
    int stride = gridDim.x * blockDim.x;
    for (int i = blockIdx.x * blockDim.x + threadIdx.x; i < N; i += stride)
        norm[i] = rsqrtf(fmaxf((float)deg[i], 1.0f));
}

__global__ void degi_kernel(const int* __restrict__ dst, int E, int* __restrict__ deg) {
    int stride = gridDim.x * blockDim.x;
    for (int i = blockIdx.x * blockDim.x + threadIdx.x; i < E; i += stride)
        atomicAdd(&deg[dst[i]], 1);
}

// ---------------- fp16 staging + gathers ----------------

// y[n][d] = fp16(feat[n][d] * norm[n])
__global__ void yconv_kernel(const float* __restrict__ feat, const float* __restrict__ norm,
                             __half* __restrict__ y, int N) {
    long total = (long)N * 32;
    long stride = (long)gridDim.x * blockDim.x;
    const float4* f4 = reinterpret_cast<const float4*>(feat);
    uint2* y2 = reinterpret_cast<uint2*>(y);
    for (long i = (long)blockIdx.x * blockDim.x + threadIdx.x; i < total; i += stride) {
        int n = (int)(i >> 5);
        float nm = norm[n];
        float4 v = f4[i];
        U8 o;
        o.h[0] = __floats2half2_rn(v.x * nm, v.y * nm);
        o.h[1] = __floats2half2_rn(v.z * nm, v.w * nm);
        y2[i] = o.u;
    }
}

// aggh[n] = fp16( norm[n] * sum_j y[esrc[j]] ) ; 16 lanes per node (dst-norm folded in).
__global__ void gather1_kernel(const __half* __restrict__ y, const int* __restrict__ rowptr,
                               const int* __restrict__ esrc, const int* __restrict__ perm,
                               const float* __restrict__ norm,
                               __half* __restrict__ aggh, int N) {
    int lane = threadIdx.x & 15;
    long g = ((long)blockIdx.x * blockDim.x + threadIdx.x) >> 4;
    long gstride = ((long)gridDim.x * blockDim.x) >> 4;
    const uint4* y4 = reinterpret_cast<const uint4*>(y);
    uint4* a4 = reinterpret_cast<uint4*>(aggh);
    for (long gi = g; gi < N; gi += gstride) {
        int n = perm[gi];
        int beg = rowptr[n], end = rowptr[n + 1];
        float a0 = 0.f, a1 = 0.f, a2 = 0.f, a3 = 0.f;
        float a4f = 0.f, a5 = 0.f, a6 = 0.f, a7 = 0.f;
        int j = beg;
        for (; j + 1 < end; j += 2) {
            int s0 = esrc[j], s1 = esrc[j + 1];
            U16 u0, u1;
            u0.u = y4[(long)s0 * 16 + lane];
            u1.u = y4[(long)s1 * 16 + lane];
            float2 p0 = __half22float2(u0.h[0]), p1 = __half22float2(u0.h[1]);
            float2 p2 = __half22float2(u0.h[2]), p3 = __half22float2(u0.h[3]);
            float2 q0 = __half22float2(u1.h[0]), q1 = __half22float2(u1.h[1]);
            float2 q2 = __half22float2(u1.h[2]), q3 = __half22float2(u1.h[3]);
            a0 += p0.x + q0.x; a1 += p0.y + q0.y;
            a2 += p1.x + q1.x; a3 += p1.y + q1.y;
            a4f += p2.x + q2.x; a5 += p2.y + q2.y;
            a6 += p3.x + q3.x; a7 += p3.y + q3.y;
        }
        if (j < end) {
            int s0 = esrc[j];
            U16 u0; u0.u = y4[(long)s0 * 16 + lane];
            float2 p0 = __half22float2(u0.h[0]), p1 = __half22float2(u0.h[1]);
            float2 p2 = __half22float2(u0.h[2]), p3 = __half22float2(u0.h[3]);
            a0 += p0.x; a1 += p0.y; a2 += p1.x; a3 += p1.y;
            a4f += p2.x; a5 += p2.y; a6 += p3.x; a7 += p3.y;
        }
        float nm = norm[n];
        U16 o;
        o.h[0] = __floats2half2_rn(a0 * nm, a1 * nm);
        o.h[1] = __floats2half2_rn(a2 * nm, a3 * nm);
        o.h[2] = __floats2half2_rn(a4f * nm, a5 * nm);
        o.h[3] = __floats2half2_rn(a6 * nm, a7 * nm);
        a4[(long)n * 16 + lane] = o.u;
    }
}

// out[n] = norm[n] * sum_j z[esrc[j]] + b2 ; 12 nodes/wave, 5 lanes x uint4 per node.
__global__ void gather2_kernel(const __half* __restrict__ z, const int* __restrict__ rowptr,
                               const int* __restrict__ esrc, const int* __restrict__ perm,
                               const float* __restrict__ norm, const float* __restrict__ b2,
                               float* __restrict__ out, int N) {
    int lane = threadIdx.x & 63;
    int grp = lane / 5;             // 0..12 (12 => inactive, lanes 60-63)
    int seg = lane - grp * 5;       // 0..4
    bool act = grp < 12;
    long wglob = ((long)blockIdx.x * blockDim.x + threadIdx.x) >> 6;
    long g0 = wglob * 12 + grp;
    long gstride = (((long)gridDim.x * blockDim.x) >> 6) * 12;
    const uint4* z4 = reinterpret_cast<const uint4*>(z);   // row = 5 uint4 (80B)
    for (long gi = g0; gi < N; gi += gstride) {
        if (act) {
            int n = perm[gi];
            int beg = rowptr[n], end = rowptr[n + 1];
            float a0 = 0.f, a1 = 0.f, a2 = 0.f, a3 = 0.f;
            float a4f = 0.f, a5 = 0.f, a6 = 0.f, a7 = 0.f;
            int j = beg;
            for (; j + 1 < end; j += 2) {
                int s0 = esrc[j], s1 = esrc[j + 1];
                U16 u0, u1;
                u0.u = z4[(long)s0 * 5 + seg];
                u1.u = z4[(long)s1 * 5 + seg];
                float2 p0 = __half22float2(u0.h[0]), p1 = __half22float2(u0.h[1]);
                float2 p2 = __half22float2(u0.h[2]), p3 = __half22float2(u0.h[3]);
                float2 q0 = __half22float2(u1.h[0]), q1 = __half22float2(u1.h[1]);
                float2 q2 = __half22float2(u1.h[2]), q3 = __half22float2(u1.h[3]);
                a0 += p0.x + q0.x; a1 += p0.y + q0.y;
                a2 += p1.x + q1.x; a3 += p1.y + q1.y;
                a4f += p2.x + q2.x; a5 += p2.y + q2.y;
                a6 += p3.x + q3.x; a7 += p3.y + q3.y;
            }
            if (j < end) {
                int s0 = esrc[j];
                U16 u0; u0.u = z4[(long)s0 * 5 + seg];
                float2 p0 = __half22float2(u0.h[0]), p1 = __half22float2(u0.h[1]);
                float2 p2 = __half22float2(u0.h[2]), p3 = __half22float2(u0.h[3]);
                a0 += p0.x; a1 += p0.y; a2 += p1.x; a3 += p1.y;
                a4f += p2.x; a5 += p2.y; a6 += p3.x; a7 += p3.y;
            }
            float nm = norm[n];
            const float4* b4 = reinterpret_cast<const float4*>(b2);
            float4 bb0 = b4[seg * 2], bb1 = b4[seg * 2 + 1];
            FV4 o0, o1;
            o0.h.x = fmaf(a0, nm, bb0.x); o0.h.y = fmaf(a1, nm, bb0.y);
            o0.h.z = fmaf(a2, nm, bb0.z); o0.h.w = fmaf(a3, nm, bb0.w);
            o1.h.x = fmaf(a4f, nm, bb1.x); o1.h.y = fmaf(a5, nm, bb1.y);
            o1.h.z = fmaf(a6, nm, bb1.z); o1.h.w = fmaf(a7, nm, bb1.w);
            f32x4* out4 = reinterpret_cast<f32x4*>(out);
            __builtin_nontemporal_store(o0.v, &out4[(long)n * 10 + seg * 2]);
            __builtin_nontemporal_store(o1.v, &out4[(long)n * 10 + seg * 2 + 1]);
        }
    }
}

// ---------------- MFMA fused matmul ----------------

// Pre-pack W1 [128][128] f32 and W2 [128][40] f32 (padded to 48 cols) into fp16
// MFMA B-fragments: frag[(c*4+t)*64 + lane][j] = W[t*32 + (lane>>4)*8 + j][c*16 + (lane&15)]
__global__ void wprep_kernel(const float* __restrict__ W1, const float* __restrict__ W2,
                             __half* __restrict__ w1f, __half* __restrict__ w2f) {
    int tid = blockIdx.x * blockDim.x + threadIdx.x;
    if (tid < 2048) {
        int l = tid & 63;
        int t = (tid >> 6) & 3;
        int c = tid >> 8;
        int kb = t * 32 + (l >> 4) * 8, col = c * 16 + (l & 15);
        #pragma unroll
        for (int j = 0; j < 8; ++j)
            w1f[tid * 8 + j] = __float2half_rn(W1[(kb + j) * DHID + col]);
    } else if (tid < 2048 + 768) {
        int id = tid - 2048;
        int l = id & 63;
        int t = (id >> 6) & 3;
        int c = id >> 8;
        int kb = t * 32 + (l >> 4) * 8, col = c * 16 + (l & 15);
        #pragma unroll
        for (int j = 0; j < 8; ++j)
            w2f[id * 8 + j] = (col < DOUT) ? __float2half_rn(W2[(kb + j) * DOUT + col])
                                           : __float2half_rn(0.f);
    }
}

// Fused: h = elu(aggh @ W1 + b1) staged in swizzled LDS (per-wave 16 rows),
//        z = fp16(norm * (h @ W2)). 64 rows/block, 4 waves.
__launch_bounds__(256, 2)
__global__ void mmfused_kernel(const __half* __restrict__ aggh,
                               const __half* __restrict__ w1f, const __half* __restrict__ w2f,
                               const float* __restrict__ b1, const float* __restrict__ norm,
                               __half* __restrict__ z, int N) {
    __shared__ uint4 w1l[2048];              // 32KB
    __shared__ uint4 w2l[768];               // 12KB
    __shared__ unsigned short hl[64 * 128];  // 16KB, XOR-swizzled
    int tid = threadIdx.x;
    const uint4* w1g = reinterpret_cast<const uint4*>(w1f);
    const uint4* w2g = reinterpret_cast<const uint4*>(w2f);
    for (int i = tid; i < 2048; i += 256) w1l[i] = w1g[i];
    for (int i = tid; i < 768; i += 256) w2l[i] = w2g[i];
    __syncthreads();

    int w = tid >> 6, l = tid & 63;
    int lr = l & 15, lg = l >> 4;
    float b1v[8];
    #pragma unroll
    for (int c = 0; c < 8; ++c) b1v[c] = b1[c * 16 + lr];

    int ntiles = (N + 63) >> 6;
    const uint4* ag = reinterpret_cast<const uint4*>(aggh);
    for (int tile = blockIdx.x; tile < ntiles; tile += gridDim.x) {
        int rb = tile << 6;
        int arow = rb + w * 16 + lr;
        int arc = min(arow, N - 1);
        F16X8 af[4];
        #pragma unroll
        for (int t = 0; t < 4; ++t) af[t].u = ag[(long)arc * 16 + t * 4 + lg];
        #pragma unroll
        for (int c = 0; c < 8; ++c) {
            f32x4 acc = {b1v[c], b1v[c], b1v[c], b1v[c]};
            #pragma unroll
            for (int t = 0; t < 4; ++t) {
                F16X8 bf; bf.u = w1l[(c * 4 + t) * 64 + l];
                acc = __builtin_amdgcn_mfma_f32_16x16x32_f16(af[t].f, bf.f, acc, 0, 0, 0);
            }
            int colb2 = (c * 16 + lr) * 2;
            #pragma unroll
            for (int i = 0; i < 4; ++i) {
                int rl = w * 16 + lg * 4 + i;
                HCV cv; cv.h = __float2half_rn(elu_f(acc[i]));
                int ba = (rl * 256 + colb2) ^ ((rl & 7) << 4);
                *reinterpret_cast<unsigned short*>(reinterpret_cast<char*>(hl) + ba) = cv.s;
            }
        }
        int rl2 = w * 16 + lr;
        int sw = (rl2 & 7) << 4;
        F16X8 hf[4];
        #pragma unroll
        for (int t = 0; t < 4; ++t) {
            int ba = (rl2 * 256 + (t * 32 + lg * 8) * 2) ^ sw;
            hf[t].u = *reinterpret_cast<const uint4*>(reinterpret_cast<const char*>(hl) + ba);
        }
        float nmv[4];
        #pragma unroll
        for (int i = 0; i < 4; ++i) {
            int r = rb + w * 16 + lg * 4 + i;
            nmv[i] = norm[min(r, N - 1)];
        }
        #pragma unroll
        for (int c = 0; c < 3; ++c) {
            f32x4 acc = {0.f, 0.f, 0.f, 0.f};
            #pragma unroll
            for (int t = 0; t < 4; ++t) {
                F16X8 bf; bf.u = w2l[(c * 4 + t) * 64 + l];
                acc = __builtin_amdgcn_mfma_f32_16x16x32_f16(hf[t].f, bf.f, acc, 0, 0, 0);
            }
            int col = c * 16 + lr;
            if (col < DOUT) {
                #pragma unroll
                for (int i = 0; i < 4; ++i) {
                    int r = rb + w * 16 + lg * 4 + i;
                    if (r < N) z[(long)r * DOUT + col] = __float2half_rn(acc[i] * nmv[i]);
                }
            }
        }
    }
}

// ---------------- fallback (f32 atomic path) ----------------

__global__ void scatter1_kernel(const float* __restrict__ feat, const int* __restrict__ src,
                                const int* __restrict__ dst, const float* __restrict__ norm,
                                float* __restrict__ agg, int E) {
    long T = (long)blockIdx.x * blockDim.x + threadIdx.x;
    int l4 = (int)(T & 31);
    long e = T >> 5;
    long estride = ((long)gridDim.x * blockDim.x) >> 5;
    for (; e < E; e += estride) {
        int s = src[e], d = dst[e];
        float ns = norm[s];
        float4 v = reinterpret_cast<const float4*>(feat)[(long)s * 32 + l4];
        float* o = agg + (long)d * DIN + l4 * 4;
        atomicAdd(o + 0, v.x * ns);
        atomicAdd(o + 1, v.y * ns);
        atomicAdd(o + 2, v.z * ns);
        atomicAdd(o + 3, v.w * ns);
    }
}

__global__ void scatter2_kernel(const float* __restrict__ z, const int* __restrict__ src,
                                const int* __restrict__ dst, float* __restrict__ out, int E) {
    long T = (long)blockIdx.x * blockDim.x + threadIdx.x;
    int l = (int)(T & 15);
    long e = T >> 4;
    long estride = ((long)gridDim.x * blockDim.x) >> 4;
    for (; e < E; e += estride) {
        if (l < 10) {
            int s = src[e], d = dst[e];
            float4 v = reinterpret_cast<const float4*>(z)[(long)s * 10 + l];
            float* o = out + (long)d * DOUT + l * 4;
            atomicAdd(o + 0, v.x);
            atomicAdd(o + 1, v.y);
            atomicAdd(o + 2, v.z);
            atomicAdd(o + 3, v.w);
        }
    }
}

__launch_bounds__(256, 2)
__global__ void mm1f_kernel(float* __restrict__ xh, const float* __restrict__ W1,
                            const float* __restrict__ b1, const float* __restrict__ norm,
                            int N) {
    __shared__ float Wl[DIN * DHID];
    __shared__ float Xl[32 * DIN];
    for (int i = threadIdx.x; i < DIN * DHID; i += 256) Wl[i] = W1[i];
    int cg = threadIdx.x & 31;
    int rg = threadIdx.x >> 5;
    int c0 = cg * 4;
    for (long r0 = (long)blockIdx.x * 32; r0 < N; r0 += (long)gridDim.x * 32) {
        __syncthreads();
        for (int i = threadIdx.x; i < 32 * 32; i += 256) {
            int rr = i >> 5;
            long row = r0 + rr;
            float4 v = make_float4(0.f, 0.f, 0.f, 0.f);
            if (row < N) {
                v = reinterpret_cast<const float4*>(xh)[row * 32 + (i & 31)];
                float nm = norm[row];
                v.x *= nm; v.y *= nm; v.z *= nm; v.w *= nm;
            }
            reinterpret_cast<float4*>(Xl)[i] = v;
        }
        __syncthreads();
        float acc[4][4];
        float bx = b1[c0], by = b1[c0 + 1], bz = b1[c0 + 2], bw = b1[c0 + 3];
        #pragma unroll
        for (int r = 0; r < 4; ++r) { acc[r][0] = bx; acc[r][1] = by; acc[r][2] = bz; acc[r][3] = bw; }
        for (int k = 0; k < DIN; k += 4) {
            float4 w0 = *reinterpret_cast<const float4*>(&Wl[(k + 0) * DHID + c0]);
            float4 w1 = *reinterpret_cast<const float4*>(&Wl[(k + 1) * DHID + c0]);
            float4 w2 = *reinterpret_cast<const float4*>(&Wl[(k + 2) * DHID + c0]);
            float4 w3 = *reinterpret_cast<const float4*>(&Wl[(k + 3) * DHID + c0]);
            #pragma unroll
            for (int r = 0; r < 4; ++r) {
                float4 x = *reinterpret_cast<const float4*>(&Xl[(rg * 4 + r) * DIN + k]);
                acc[r][0] = fmaf(x.x, w0.x, fmaf(x.y, w1.x, fmaf(x.z, w2.x, fmaf(x.w, w3.x, acc[r][0]))));
                acc[r][1] = fmaf(x.x, w0.y, fmaf(x.y, w1.y, fmaf(x.z, w2.y, fmaf(x.w, w3.y, acc[r][1]))));
                acc[r][2] = fmaf(x.x, w0.z, fmaf(x.y, w1.z, fmaf(x.z, w2.z, fmaf(x.w, w3.z, acc[r][2]))));
                acc[r][3] = fmaf(x.x, w0.w, fmaf(x.y, w1.w, fmaf(x.z, w2.w, fmaf(x.w, w3.w, acc[r][3]))));
            }
        }
        #pragma unroll
        for (int r = 0; r < 4; ++r) {
            long row = r0 + rg * 4 + r;
            if (row < N) {
                float4 o;
                o.x = elu_f(acc[r][0]); o.y = elu_f(acc[r][1]);
                o.z = elu_f(acc[r][2]); o.w = elu_f(acc[r][3]);
                *reinterpret_cast<float4*>(&xh[row * DIN + c0]) = o;
            }
        }
    }
}

__launch_bounds__(256, 2)
__global__ void mm2f_kernel(const float* __restrict__ h, const float* __restrict__ W2,
                            const float* __restrict__ norm, float* __restrict__ z, int N) {
    __shared__ float Wl[DHID * DOUT];
    __shared__ float Xl[64 * DIN];
    for (int i = threadIdx.x; i < DHID * DOUT; i += 256) Wl[i] = W2[i];
    int cg = threadIdx.x & 15;
    int rg = threadIdx.x >> 4;
    int c0 = cg * 4;
    for (long r0 = (long)blockIdx.x * 64; r0 < N; r0 += (long)gridDim.x * 64) {
        __syncthreads();
        for (int i = threadIdx.x; i < 64 * 32; i += 256) {
            int rr = i >> 5;
            long row = r0 + rr;
            float4 v = make_float4(0.f, 0.f, 0.f, 0.f);
            if (row < N) v = reinterpret_cast<const float4*>(h)[row * 32 + (i & 31)];
            reinterpret_cast<float4*>(Xl)[i] = v;
        }
        __syncthreads();
        if (c0 < DOUT) {
            float acc[4][4];
            #pragma unroll
            for (int r = 0; r < 4; ++r) { acc[r][0] = 0.f; acc[r][1] = 0.f; acc[r][2] = 0.f; acc[r][3] = 0.f; }
            for (int k = 0; k < DHID; k += 4) {
                float4 w0 = *reinterpret_cast<const float4*>(&Wl[(k + 0) * DOUT + c0]);
                float4 w1 = *reinterpret_cast<const float4*>(&Wl[(k + 1) * DOUT + c0]);
                float4 w2 = *reinterpret_cast<const float4*>(&Wl[(k + 2) * DOUT + c0]);
                float4 w3 = *reinterpret_cast<const float4*>(&Wl[(k + 3) * DOUT + c0]);
                #pragma unroll
                for (int r = 0; r < 4; ++r) {
                    float4 x = *reinterpret_cast<const float4*>(&Xl[(rg * 4 + r) * DIN + k]);
                    acc[r][0] = fmaf(x.x, w0.x, fmaf(x.y, w1.x, fmaf(x.z, w2.x, fmaf(x.w, w3.x, acc[r][0]))));
                    acc[r][1] = fmaf(x.x, w0.y, fmaf(x.y, w1.y, fmaf(x.z, w2.y, fmaf(x.w, w3.y, acc[r][1]))));
                    acc[r][2] = fmaf(x.x, w0.z, fmaf(x.y, w1.z, fmaf(x.z, w2.z, fmaf(x.w, w3.z, acc[r][2]))));
                    acc[r][3] = fmaf(x.x, w0.w, fmaf(x.y, w1.w, fmaf(x.z, w2.w, fmaf(x.w, w3.w, acc[r][3]))));
                }
            }
            #pragma unroll
            for (int r = 0; r < 4; ++r) {
                long row = r0 + rg * 4 + r;
                if (row < N) {
                    float nm = norm[row];
                    float4 o;
                    o.x = acc[r][0] * nm; o.y = acc[r][1] * nm;
                    o.z = acc[r][2] * nm; o.w = acc[r][3] * nm;
                    *reinterpret_cast<float4*>(&z[row * DOUT + c0]) = o;
                }
            }
        }
    }
}

__global__ void final_kernel(float* __restrict__ out, const float* __restrict__ norm,
                             const float* __restrict__ b2, int N) {
    long total = (long)N * DOUT;
    long stride = (long)gridDim.x * blockDim.x;
    for (long i = (long)blockIdx.x * blockDim.x + threadIdx.x; i < total; i += stride) {
        int n = (int)(i / DOUT), d = (int)(i % DOUT);
        out[i] = fmaf(out[i], norm[n], b2[d]);
    }
}

// ---------------- launch ----------------

static inline size_t al4k(size_t x) { return (x + 4095) & ~(size_t)4095; }

extern "C" void kernel_launch(void* const* d_in, const int* in_sizes, int n_in,
                              void* d_out, int out_size, void* d_ws, size_t ws_size,
                              hipStream_t stream) {
    const float* feat = (const float*)d_in[0];
    const int*   src  = (const int*)d_in[1];
    const int*   dst  = (const int*)d_in[2];
    const float* W1   = (const float*)d_in[3];
    const float* b1   = (const float*)d_in[4];
    const float* W2   = (const float*)d_in[5];
    const float* b2   = (const float*)d_in[6];
    int N = in_sizes[0] / DIN;
    int E = in_sizes[1];
    float* out = (float*)d_out;
    char* ws = (char*)d_ws;

    int NB = (N + BNODES - 1) >> BSHIFT;
    int cap = ((E / (NB > 0 ? NB : 1)) * 5 / 4 + 256 + 1) & ~1;

    size_t o_norm   = 0;
    size_t o_rowptr = o_norm   + al4k((size_t)N * 4);
    size_t o_bcur   = o_rowptr + al4k(((size_t)N + 1) * 4);
    size_t o_bbase  = o_bcur   + al4k((size_t)(NB + 1) * 4);
    size_t o_perm   = o_bbase  + al4k((size_t)(NB + 1) * 4);
    size_t o_esrc   = o_perm   + al4k((size_t)N * 4);
    size_t o_aggh   = o_esrc   + al4k((size_t)E * 4);       // packed bucketbuf aliases aggh
    size_t o_y      = o_aggh   + al4k((size_t)N * DIN * 2);
    size_t o_z      = o_y      + al4k((size_t)N * DIN * 2);
    size_t o_w1f    = o_z      + al4k((size_t)N * DOUT * 2);
    size_t o_w2f    = o_w1f    + al4k((size_t)16384 * 2);
    size_t need     = o_w2f    + al4k((size_t)6144 * 2);

    bool bb_fits = (size_t)NB * cap * 4 <= (size_t)N * DIN * 2;
    bool packs   = N <= (1 << 22);

    if (ws_size >= need && NB <= 256 && bb_fits && packs) {
        float*  norm   = (float*)(ws + o_norm);
        int*    rowptr = (int*)(ws + o_rowptr);
        int*    bcur   = (int*)(ws + o_bcur);
        int*    bbase  = (int*)(ws + o_bbase);
        int*    perm   = (int*)(ws + o_perm);
        int*    esrc   = (int*)(ws + o_esrc);
        __half* aggh   = (__half*)(ws + o_aggh);
        int*    bbuf   = (int*)(ws + o_aggh);
        __half* y      = (__half*)(ws + o_y);
        __half* z      = (__half*)(ws + o_z);
        __half* w1f    = (__half*)(ws + o_w1f);
        __half* w2f    = (__half*)(ws + o_w2f);

        hipMemsetAsync(bcur, 0, (size_t)(NB + 1) * 4, stream);

        wprep_kernel<<<11, 256, 0, stream>>>(W1, W2, w1f, w2f);
        int p1grid = (E + 8191) / 8192;
        pass1_bucket<<<p1grid, 256, 0, stream>>>(src, dst, E, NB, cap, bcur, bbuf);
        bucket_scan<<<1, 1, 0, stream>>>(bcur, bbase, NB);
        pass2_sort<<<NB, 256, 0, stream>>>(bbuf, bcur, bbase, N, NB, cap, norm, rowptr, esrc);
        perm_build<<<(N + 4095) / 4096, 256, 0, stream>>>(rowptr, perm, N);
        yconv_kernel<<<4096, 256, 0, stream>>>(feat, norm, y, N);

        gather1_kernel<<<(N * 16 + 255) / 256, 256, 0, stream>>>(y, rowptr, esrc, perm, norm, aggh, N);
        mmfused_kernel<<<512, 256, 0, stream>>>(aggh, w1f, w2f, b1, norm, z, N);
        gather2_kernel<<<(N + 47) / 48, 256, 0, stream>>>(z, rowptr, esrc, perm, norm, b2, out, N);
    } else {
        size_t f_norm = 0;
        size_t f_agg  = f_norm + al4k((size_t)N * 4);
        size_t f_z    = f_agg  + al4k((size_t)N * DIN * 4);
        float* norm = (float*)(ws + f_norm);
        float* agg  = (float*)(ws + f_agg);
        float* z    = (float*)(ws + f_z);
        int*   degi = (int*)(ws + f_norm);

        hipMemsetAsync(degi, 0, (size_t)N * 4, stream);
        hipMemsetAsync(agg, 0, (size_t)N * DIN * 4, stream);
        hipMemsetAsync(d_out, 0, (size_t)N * DOUT * 4, stream);

        degi_kernel<<<1024, 256, 0, stream>>>(dst, E, degi);
        norm_from_deg<<<(N + 255) / 256, 256, 0, stream>>>(degi, (float*)degi, N);
        scatter1_kernel<<<4096, 256, 0, stream>>>(feat, src, dst, norm, agg, E);
        mm1f_kernel<<<(N + 31) / 32, 256, 0, stream>>>(agg, W1, b1, norm, N);
        mm2f_kernel<<<(N + 63) / 64, 256, 0, stream>>>(agg, W2, norm, z, N);
        scatter2_kernel<<<4096, 256, 0, stream>>>(z, src, dst, out, E);
        final_kernel<<<4096, 256, 0, stream>>>(out, norm, b2, N);
    }
}

// Round 12
// 232.046 us; speedup vs baseline: 1.0474x; 1.0474x over previous
//
#include <hip/hip_runtime.h>
#include <hip/hip_fp16.h>
#include <math.h>

// SGC 2-layer: out = A_hat * elu(A_hat * X * W1 + b1) * W2 + b2
// A_hat = D^-1/2 A D^-1/2 (in-degree based, clip(deg,1))
// R2: CSR + gather (no float atomics). R4: counting-sort CSR. R5: fp16 operands.
// R6: wide loads + degree-perm. R7: MFMA fused matmul. 308->239us.
// R9/R10: bucket-local perm regressed gather1 62->74us; R11 restored chunk-4096
//     perm -> gather1 back to 62us (perm content confirmed causal).
// R12: launch consolidation: bucket_scan folded into pass2 (per-block LDS scan);
//     wprep merged into pass1; perm_build merged into yconv. 10 -> 7 dispatches.

#define DIN  128
#define DHID 128
#define DOUT 40
#define BSHIFT 9
#define BNODES 512   // 1 << BSHIFT

union U8  { uint2 u; __half2 h[2]; };
union U16 { uint4 u; __half2 h[4]; };

typedef _Float16     f16x8 __attribute__((ext_vector_type(8)));
typedef float        f32x4 __attribute__((ext_vector_type(4)));
union F16X8 { uint4 u; f16x8 f; };
union HCV   { __half h; unsigned short s; };
union FV4   { float4 h; f32x4 v; };

__device__ __forceinline__ float elu_f(float x) {
    return x > 0.0f ? x : (expf(x) - 1.0f);
}

// ---------------- merged wprep + pass1 (bucket edges by dst>>9) ----------------
// blocks 0..10: pack W1/W2 into fp16 MFMA B-fragments.
// blocks 11.. : bucket edges (packed record (s<<9)|dlocal).
__global__ void prep_pass1(const float* __restrict__ W1, const float* __restrict__ W2,
                           __half* __restrict__ w1f, __half* __restrict__ w2f,
                           const int* __restrict__ src, const int* __restrict__ dst,
                           int E, int NB, int cap,
                           int* __restrict__ bcur, int* __restrict__ bbuf) {
    __shared__ int cnt[256];
    __shared__ int wcur[256];
    if (blockIdx.x < 11) {
        int tid = blockIdx.x * 256 + threadIdx.x;
        if (tid < 2048) {
            int l = tid & 63;
            int t = (tid >> 6) & 3;
            int c = tid >> 8;
            int kb = t * 32 + (l >> 4) * 8, col = c * 16 + (l & 15);
            #pragma unroll
            for (int j = 0; j < 8; ++j)
                w1f[tid * 8 + j] = __float2half_rn(W1[(kb + j) * DHID + col]);
        } else if (tid < 2048 + 768) {
            int id = tid - 2048;
            int l = id & 63;
            int t = (id >> 6) & 3;
            int c = id >> 8;
            int kb = t * 32 + (l >> 4) * 8, col = c * 16 + (l & 15);
            #pragma unroll
            for (int j = 0; j < 8; ++j)
                w2f[id * 8 + j] = (col < DOUT) ? __float2half_rn(W2[(kb + j) * DOUT + col])
                                               : __float2half_rn(0.f);
        }
        return;
    }
    int bid = blockIdx.x - 11;
    int nblk = gridDim.x - 11;
    const int CHUNK = 8192;
    for (long base = (long)bid * CHUNK; base < E; base += (long)nblk * CHUNK) {
        int n = min(CHUNK, (int)(E - base));
        if (threadIdx.x < 256) cnt[threadIdx.x] = 0;
        __syncthreads();
        for (int i = threadIdx.x; i < n; i += blockDim.x) {
            int b = dst[base + i] >> BSHIFT;
            atomicAdd(&cnt[b], 1);
        }
        __syncthreads();
        if (threadIdx.x < NB) {
            int c = cnt[threadIdx.x];
            wcur[threadIdx.x] = (c > 0) ? atomicAdd(&bcur[threadIdx.x], c) : 0;
        }
        __syncthreads();
        for (int i = threadIdx.x; i < n; i += blockDim.x) {
            int s = src[base + i];
            int d = dst[base + i];
            int b = d >> BSHIFT;
            int slot = atomicAdd(&wcur[b], 1);
            if (slot < cap) bbuf[(long)b * cap + slot] = (s << BSHIFT) | (d & (BNODES - 1));
        }
        __syncthreads();
    }
}

// per-bucket LDS counting sort -> norm, rowptr, esrc; bucket base via in-block scan.
// REQUIRES blockDim.x == 256, NB <= 256.
__global__ void pass2_sort(const int* __restrict__ bbuf, const int* __restrict__ bcur,
                           int N, int NB, int cap,
                           float* __restrict__ norm, int* __restrict__ rowptr,
                           int* __restrict__ esrc) {
    __shared__ int cnt[BNODES];
    __shared__ int scnt[256];
    __shared__ int sgbase;
    int tid = threadIdx.x;
    int b = blockIdx.x;
    scnt[tid] = (tid < NB) ? bcur[tid] : 0;
    __syncthreads();
    if (tid == 0) {
        int run = 0;
        for (int i = 0; i < NB; ++i) { if (i == b) sgbase = run; run += scnt[i]; }
        if (b == NB - 1) rowptr[N] = run;
    }
    __syncthreads();
    int gbase = sgbase;
    int n_b = min(bcur[b], cap);
    int dbase = b << BSHIFT;
    const int* eb = bbuf + (long)b * cap;
    for (int i = tid; i < BNODES; i += blockDim.x) cnt[i] = 0;
    __syncthreads();
    for (int i = tid; i < n_b; i += blockDim.x)
        atomicAdd(&cnt[eb[i] & (BNODES - 1)], 1);
    __syncthreads();
    for (int i = tid; i < BNODES; i += blockDim.x) {
        int d = dbase + i;
        if (d < N) norm[d] = rsqrtf(fmaxf((float)cnt[i], 1.0f));
    }
    __syncthreads();
    if (tid == 0) {
        int run = 0;
        #pragma unroll 4
        for (int i = 0; i < BNODES; ++i) { int c = cnt[i]; cnt[i] = run; run += c; }
    }
    __syncthreads();
    for (int i = tid; i < BNODES; i += blockDim.x) {
        int d = dbase + i;
        if (d < N) rowptr[d] = gbase + cnt[i];
    }
    __syncthreads();
    for (int i = tid; i < n_b; i += blockDim.x) {
        int v = eb[i];
        int slot = atomicAdd(&cnt[v & (BNODES - 1)], 1);
        esrc[gbase + slot] = ((unsigned)v) >> BSHIFT;
    }
}

// ---------------- merged perm_build + yconv ----------------
// blocks 0..npermblk-1: chunk-4096 degree counting-sort -> perm (R7-exact content).
// blocks npermblk..   : y[n][d] = fp16(feat[n][d] * norm[n]).
__global__ void perm_yconv(const int* __restrict__ rowptr, int* __restrict__ perm,
                           const float* __restrict__ feat, const float* __restrict__ norm,
                           __half* __restrict__ y, int N, int npermblk) {
    __shared__ int lcnt[1024];
    __shared__ int lbase[1024];
    if ((int)blockIdx.x < npermblk) {
        const int CHUNK = 4096;
        for (long base = (long)blockIdx.x * CHUNK; base < N; base += (long)npermblk * CHUNK) {
            int n = min(CHUNK, (int)(N - base));
            for (int i = threadIdx.x; i < 1024; i += 256) lcnt[i] = 0;
            __syncthreads();
            for (int i = threadIdx.x; i < n; i += 256) {
                int d = min(rowptr[base + i + 1] - rowptr[base + i], 1023);
                atomicAdd(&lcnt[d], 1);
            }
            __syncthreads();
            if (threadIdx.x == 0) {
                int run = 0;
                for (int i = 0; i < 1024; ++i) { int c = lcnt[i]; lbase[i] = run; run += c; }
            }
            __syncthreads();
            for (int i = threadIdx.x; i < 1024; i += 256) lcnt[i] = 0;
            __syncthreads();
            for (int i = threadIdx.x; i < n; i += 256) {
                int d = min(rowptr[base + i + 1] - rowptr[base + i], 1023);
                int pos = lbase[d] + atomicAdd(&lcnt[d], 1);
                perm[base + pos] = base + (int)i;
            }
            __syncthreads();
        }
        return;
    }
    long total = (long)N * 32;
    long stride = (long)(gridDim.x - npermblk) * 256;
    const float4* f4 = reinterpret_cast<const float4*>(feat);
    uint2* y2 = reinterpret_cast<uint2*>(y);
    for (long i = (long)(blockIdx.x - npermblk) * 256 + threadIdx.x; i < total; i += stride) {
        int n = (int)(i >> 5);
        float nm = norm[n];
        float4 v = f4[i];
        U8 o;
        o.h[0] = __floats2half2_rn(v.x * nm, v.y * nm);
        o.h[1] = __floats2half2_rn(v.z * nm, v.w * nm);
        y2[i] = o.u;
    }
}

__global__ void norm_from_deg(const int* __restrict__ deg, float* __restrict__ norm, int N) {
    int stride = gridDim.x * blockDim.x;
    for (int i = blockIdx.x * blockDim.x + threadIdx.x; i < N; i += stride)
        norm[i] = rsqrtf(fmaxf((float)deg[i], 1.0f));
}

__global__ void degi_kernel(const int* __restrict__ dst, int E, int* __restrict__ deg) {
    int stride = gridDim.x * blockDim.x;
    for (int i = blockIdx.x * blockDim.x + threadIdx.x; i < E; i += stride)
        atomicAdd(&deg[dst[i]], 1);
}

// ---------------- gathers ----------------

// aggh[n] = fp16( norm[n] * sum_j y[esrc[j]] ) ; 16 lanes per node (dst-norm folded in).
__global__ void gather1_kernel(const __half* __restrict__ y, const int* __restrict__ rowptr,
                               const int* __restrict__ esrc, const int* __restrict__ perm,
                               const float* __restrict__ norm,
                               __half* __restrict__ aggh, int N) {
    int lane = threadIdx.x & 15;
    long g = ((long)blockIdx.x * blockDim.x + threadIdx.x) >> 4;
    long gstride = ((long)gridDim.x * blockDim.x) >> 4;
    const uint4* y4 = reinterpret_cast<const uint4*>(y);
    uint4* a4 = reinterpret_cast<uint4*>(aggh);
    for (long gi = g; gi < N; gi += gstride) {
        int n = perm[gi];
        int beg = rowptr[n], end = rowptr[n + 1];
        float a0 = 0.f, a1 = 0.f, a2 = 0.f, a3 = 0.f;
        float a4f = 0.f, a5 = 0.f, a6 = 0.f, a7 = 0.f;
        int j = beg;
        for (; j + 1 < end; j += 2) {
            int s0 = esrc[j], s1 = esrc[j + 1];
            U16 u0, u1;
            u0.u = y4[(long)s0 * 16 + lane];
            u1.u = y4[(long)s1 * 16 + lane];
            float2 p0 = __half22float2(u0.h[0]), p1 = __half22float2(u0.h[1]);
            float2 p2 = __half22float2(u0.h[2]), p3 = __half22float2(u0.h[3]);
            float2 q0 = __half22float2(u1.h[0]), q1 = __half22float2(u1.h[1]);
            float2 q2 = __half22float2(u1.h[2]), q3 = __half22float2(u1.h[3]);
            a0 += p0.x + q0.x; a1 += p0.y + q0.y;
            a2 += p1.x + q1.x; a3 += p1.y + q1.y;
            a4f += p2.x + q2.x; a5 += p2.y + q2.y;
            a6 += p3.x + q3.x; a7 += p3.y + q3.y;
        }
        if (j < end) {
            int s0 = esrc[j];
            U16 u0; u0.u = y4[(long)s0 * 16 + lane];
            float2 p0 = __half22float2(u0.h[0]), p1 = __half22float2(u0.h[1]);
            float2 p2 = __half22float2(u0.h[2]), p3 = __half22float2(u0.h[3]);
            a0 += p0.x; a1 += p0.y; a2 += p1.x; a3 += p1.y;
            a4f += p2.x; a5 += p2.y; a6 += p3.x; a7 += p3.y;
        }
        float nm = norm[n];
        U16 o;
        o.h[0] = __floats2half2_rn(a0 * nm, a1 * nm);
        o.h[1] = __floats2half2_rn(a2 * nm, a3 * nm);
        o.h[2] = __floats2half2_rn(a4f * nm, a5 * nm);
        o.h[3] = __floats2half2_rn(a6 * nm, a7 * nm);
        a4[(long)n * 16 + lane] = o.u;
    }
}

// out[n] = norm[n] * sum_j z[esrc[j]] + b2 ; 12 nodes/wave, 5 lanes x uint4 per node.
__global__ void gather2_kernel(const __half* __restrict__ z, const int* __restrict__ rowptr,
                               const int* __restrict__ esrc, const int* __restrict__ perm,
                               const float* __restrict__ norm, const float* __restrict__ b2,
                               float* __restrict__ out, int N) {
    int lane = threadIdx.x & 63;
    int grp = lane / 5;
    int seg = lane - grp * 5;
    bool act = grp < 12;
    long wglob = ((long)blockIdx.x * blockDim.x + threadIdx.x) >> 6;
    long g0 = wglob * 12 + grp;
    long gstride = (((long)gridDim.x * blockDim.x) >> 6) * 12;
    const uint4* z4 = reinterpret_cast<const uint4*>(z);
    for (long gi = g0; gi < N; gi += gstride) {
        if (act) {
            int n = perm[gi];
            int beg = rowptr[n], end = rowptr[n + 1];
            float a0 = 0.f, a1 = 0.f, a2 = 0.f, a3 = 0.f;
            float a4f = 0.f, a5 = 0.f, a6 = 0.f, a7 = 0.f;
            int j = beg;
            for (; j + 1 < end; j += 2) {
                int s0 = esrc[j], s1 = esrc[j + 1];
                U16 u0, u1;
                u0.u = z4[(long)s0 * 5 + seg];
                u1.u = z4[(long)s1 * 5 + seg];
                float2 p0 = __half22float2(u0.h[0]), p1 = __half22float2(u0.h[1]);
                float2 p2 = __half22float2(u0.h[2]), p3 = __half22float2(u0.h[3]);
                float2 q0 = __half22float2(u1.h[0]), q1 = __half22float2(u1.h[1]);
                float2 q2 = __half22float2(u1.h[2]), q3 = __half22float2(u1.h[3]);
                a0 += p0.x + q0.x; a1 += p0.y + q0.y;
                a2 += p1.x + q1.x; a3 += p1.y + q1.y;
                a4f += p2.x + q2.x; a5 += p2.y + q2.y;
                a6 += p3.x + q3.x; a7 += p3.y + q3.y;
            }
            if (j < end) {
                int s0 = esrc[j];
                U16 u0; u0.u = z4[(long)s0 * 5 + seg];
                float2 p0 = __half22float2(u0.h[0]), p1 = __half22float2(u0.h[1]);
                float2 p2 = __half22float2(u0.h[2]), p3 = __half22float2(u0.h[3]);
                a0 += p0.x; a1 += p0.y; a2 += p1.x; a3 += p1.y;
                a4f += p2.x; a5 += p2.y; a6 += p3.x; a7 += p3.y;
            }
            float nm = norm[n];
            const float4* b4 = reinterpret_cast<const float4*>(b2);
            float4 bb0 = b4[seg * 2], bb1 = b4[seg * 2 + 1];
            FV4 o0, o1;
            o0.h.x = fmaf(a0, nm, bb0.x); o0.h.y = fmaf(a1, nm, bb0.y);
            o0.h.z = fmaf(a2, nm, bb0.z); o0.h.w = fmaf(a3, nm, bb0.w);
            o1.h.x = fmaf(a4f, nm, bb1.x); o1.h.y = fmaf(a5, nm, bb1.y);
            o1.h.z = fmaf(a6, nm, bb1.z); o1.h.w = fmaf(a7, nm, bb1.w);
            f32x4* out4 = reinterpret_cast<f32x4*>(out);
            __builtin_nontemporal_store(o0.v, &out4[(long)n * 10 + seg * 2]);
            __builtin_nontemporal_store(o1.v, &out4[(long)n * 10 + seg * 2 + 1]);
        }
    }
}

// ---------------- MFMA fused matmul ----------------

// Fused: h = elu(aggh @ W1 + b1) staged in swizzled LDS (per-wave 16 rows),
//        z = fp16(norm * (h @ W2)). 64 rows/block, 4 waves.
__launch_bounds__(256, 2)
__global__ void mmfused_kernel(const __half* __restrict__ aggh,
                               const __half* __restrict__ w1f, const __half* __restrict__ w2f,
                               const float* __restrict__ b1, const float* __restrict__ norm,
                               __half* __restrict__ z, int N) {
    __shared__ uint4 w1l[2048];
    __shared__ uint4 w2l[768];
    __shared__ unsigned short hl[64 * 128];
    int tid = threadIdx.x;
    const uint4* w1g = reinterpret_cast<const uint4*>(w1f);
    const uint4* w2g = reinterpret_cast<const uint4*>(w2f);
    for (int i = tid; i < 2048; i += 256) w1l[i] = w1g[i];
    for (int i = tid; i < 768; i += 256) w2l[i] = w2g[i];
    __syncthreads();

    int w = tid >> 6, l = tid & 63;
    int lr = l & 15, lg = l >> 4;
    float b1v[8];
    #pragma unroll
    for (int c = 0; c < 8; ++c) b1v[c] = b1[c * 16 + lr];

    int ntiles = (N + 63) >> 6;
    const uint4* ag = reinterpret_cast<const uint4*>(aggh);
    for (int tile = blockIdx.x; tile < ntiles; tile += gridDim.x) {
        int rb = tile << 6;
        int arow = rb + w * 16 + lr;
        int arc = min(arow, N - 1);
        F16X8 af[4];
        #pragma unroll
        for (int t = 0; t < 4; ++t) af[t].u = ag[(long)arc * 16 + t * 4 + lg];
        #pragma unroll
        for (int c = 0; c < 8; ++c) {
            f32x4 acc = {b1v[c], b1v[c], b1v[c], b1v[c]};
            #pragma unroll
            for (int t = 0; t < 4; ++t) {
                F16X8 bf; bf.u = w1l[(c * 4 + t) * 64 + l];
                acc = __builtin_amdgcn_mfma_f32_16x16x32_f16(af[t].f, bf.f, acc, 0, 0, 0);
            }
            int colb2 = (c * 16 + lr) * 2;
            #pragma unroll
            for (int i = 0; i < 4; ++i) {
                int rl = w * 16 + lg * 4 + i;
                HCV cv; cv.h = __float2half_rn(elu_f(acc[i]));
                int ba = (rl * 256 + colb2) ^ ((rl & 7) << 4);
                *reinterpret_cast<unsigned short*>(reinterpret_cast<char*>(hl) + ba) = cv.s;
            }
        }
        int rl2 = w * 16 + lr;
        int sw = (rl2 & 7) << 4;
        F16X8 hf[4];
        #pragma unroll
        for (int t = 0; t < 4; ++t) {
            int ba = (rl2 * 256 + (t * 32 + lg * 8) * 2) ^ sw;
            hf[t].u = *reinterpret_cast<const uint4*>(reinterpret_cast<const char*>(hl) + ba);
        }
        float nmv[4];
        #pragma unroll
        for (int i = 0; i < 4; ++i) {
            int r = rb + w * 16 + lg * 4 + i;
            nmv[i] = norm[min(r, N - 1)];
        }
        #pragma unroll
        for (int c = 0; c < 3; ++c) {
            f32x4 acc = {0.f, 0.f, 0.f, 0.f};
            #pragma unroll
            for (int t = 0; t < 4; ++t) {
                F16X8 bf; bf.u = w2l[(c * 4 + t) * 64 + l];
                acc = __builtin_amdgcn_mfma_f32_16x16x32_f16(hf[t].f, bf.f, acc, 0, 0, 0);
            }
            int col = c * 16 + lr;
            if (col < DOUT) {
                #pragma unroll
                for (int i = 0; i < 4; ++i) {
                    int r = rb + w * 16 + lg * 4 + i;
                    if (r < N) z[(long)r * DOUT + col] = __float2half_rn(acc[i] * nmv[i]);
                }
            }
        }
    }
}

// ---------------- fallback (f32 atomic path) ----------------

__global__ void scatter1_kernel(const float* __restrict__ feat, const int* __restrict__ src,
                                const int* __restrict__ dst, const float* __restrict__ norm,
                                float* __restrict__ agg, int E) {
    long T = (long)blockIdx.x * blockDim.x + threadIdx.x;
    int l4 = (int)(T & 31);
    long e = T >> 5;
    long estride = ((long)gridDim.x * blockDim.x) >> 5;
    for (; e < E; e += estride) {
        int s = src[e], d = dst[e];
        float ns = norm[s];
        float4 v = reinterpret_cast<const float4*>(feat)[(long)s * 32 + l4];
        float* o = agg + (long)d * DIN + l4 * 4;
        atomicAdd(o + 0, v.x * ns);
        atomicAdd(o + 1, v.y * ns);
        atomicAdd(o + 2, v.z * ns);
        atomicAdd(o + 3, v.w * ns);
    }
}

__global__ void scatter2_kernel(const float* __restrict__ z, const int* __restrict__ src,
                                const int* __restrict__ dst, float* __restrict__ out, int E) {
    long T = (long)blockIdx.x * blockDim.x + threadIdx.x;
    int l = (int)(T & 15);
    long e = T >> 4;
    long estride = ((long)gridDim.x * blockDim.x) >> 4;
    for (; e < E; e += estride) {
        if (l < 10) {
            int s = src[e], d = dst[e];
            float4 v = reinterpret_cast<const float4*>(z)[(long)s * 10 + l];
            float* o = out + (long)d * DOUT + l * 4;
            atomicAdd(o + 0, v.x);
            atomicAdd(o + 1, v.y);
            atomicAdd(o + 2, v.z);
            atomicAdd(o + 3, v.w);
        }
    }
}

__launch_bounds__(256, 2)
__global__ void mm1f_kernel(float* __restrict__ xh, const float* __restrict__ W1,
                            const float* __restrict__ b1, const float* __restrict__ norm,
                            int N) {
    __shared__ float Wl[DIN * DHID];
    __shared__ float Xl[32 * DIN];
    for (int i = threadIdx.x; i < DIN * DHID; i += 256) Wl[i] = W1[i];
    int cg = threadIdx.x & 31;
    int rg = threadIdx.x >> 5;
    int c0 = cg * 4;
    for (long r0 = (long)blockIdx.x * 32; r0 < N; r0 += (long)gridDim.x * 32) {
        __syncthreads();
        for (int i = threadIdx.x; i < 32 * 32; i += 256) {
            int rr = i >> 5;
            long row = r0 + rr;
            float4 v = make_float4(0.f, 0.f, 0.f, 0.f);
            if (row < N) {
                v = reinterpret_cast<const float4*>(xh)[row * 32 + (i & 31)];
                float nm = norm[row];
                v.x *= nm; v.y *= nm; v.z *= nm; v.w *= nm;
            }
            reinterpret_cast<float4*>(Xl)[i] = v;
        }
        __syncthreads();
        float acc[4][4];
        float bx = b1[c0], by = b1[c0 + 1], bz = b1[c0 + 2], bw = b1[c0 + 3];
        #pragma unroll
        for (int r = 0; r < 4; ++r) { acc[r][0] = bx; acc[r][1] = by; acc[r][2] = bz; acc[r][3] = bw; }
        for (int k = 0; k < DIN; k += 4) {
            float4 w0 = *reinterpret_cast<const float4*>(&Wl[(k + 0) * DHID + c0]);
            float4 w1 = *reinterpret_cast<const float4*>(&Wl[(k + 1) * DHID + c0]);
            float4 w2 = *reinterpret_cast<const float4*>(&Wl[(k + 2) * DHID + c0]);
            float4 w3 = *reinterpret_cast<const float4*>(&Wl[(k + 3) * DHID + c0]);
            #pragma unroll
            for (int r = 0; r < 4; ++r) {
                float4 x = *reinterpret_cast<const float4*>(&Xl[(rg * 4 + r) * DIN + k]);
                acc[r][0] = fmaf(x.x, w0.x, fmaf(x.y, w1.x, fmaf(x.z, w2.x, fmaf(x.w, w3.x, acc[r][0]))));
                acc[r][1] = fmaf(x.x, w0.y, fmaf(x.y, w1.y, fmaf(x.z, w2.y, fmaf(x.w, w3.y, acc[r][1]))));
                acc[r][2] = fmaf(x.x, w0.z, fmaf(x.y, w1.z, fmaf(x.z, w2.z, fmaf(x.w, w3.z, acc[r][2]))));
                acc[r][3] = fmaf(x.x, w0.w, fmaf(x.y, w1.w, fmaf(x.z, w2.w, fmaf(x.w, w3.w, acc[r][3]))));
            }
        }
        #pragma unroll
        for (int r = 0; r < 4; ++r) {
            long row = r0 + rg * 4 + r;
            if (row < N) {
                float4 o;
                o.x = elu_f(acc[r][0]); o.y = elu_f(acc[r][1]);
                o.z = elu_f(acc[r][2]); o.w = elu_f(acc[r][3]);
                *reinterpret_cast<float4*>(&xh[row * DIN + c0]) = o;
            }
        }
    }
}

__launch_bounds__(256, 2)
__global__ void mm2f_kernel(const float* __restrict__ h, const float* __restrict__ W2,
                            const float* __restrict__ norm, float* __restrict__ z, int N) {
    __shared__ float Wl[DHID * DOUT];
    __shared__ float Xl[64 * DIN];
    for (int i = threadIdx.x; i < DHID * DOUT; i += 256) Wl[i] = W2[i];
    int cg = threadIdx.x & 15;
    int rg = threadIdx.x >> 4;
    int c0 = cg * 4;
    for (long r0 = (long)blockIdx.x * 64; r0 < N; r0 += (long)gridDim.x * 64) {
        __syncthreads();
        for (int i = threadIdx.x; i < 64 * 32; i += 256) {
            int rr = i >> 5;
            long row = r0 + rr;
            float4 v = make_float4(0.f, 0.f, 0.f, 0.f);
            if (row < N) v = reinterpret_cast<const float4*>(h)[row * 32 + (i & 31)];
            reinterpret_cast<float4*>(Xl)[i] = v;
        }
        __syncthreads();
        if (c0 < DOUT) {
            float acc[4][4];
            #pragma unroll
            for (int r = 0; r < 4; ++r) { acc[r][0] = 0.f; acc[r][1] = 0.f; acc[r][2] = 0.f; acc[r][3] = 0.f; }
            for (int k = 0; k < DHID; k += 4) {
                float4 w0 = *reinterpret_cast<const float4*>(&Wl[(k + 0) * DOUT + c0]);
                float4 w1 = *reinterpret_cast<const float4*>(&Wl[(k + 1) * DOUT + c0]);
                float4 w2 = *reinterpret_cast<const float4*>(&Wl[(k + 2) * DOUT + c0]);
                float4 w3 = *reinterpret_cast<const float4*>(&Wl[(k + 3) * DOUT + c0]);
                #pragma unroll
                for (int r = 0; r < 4; ++r) {
                    float4 x = *reinterpret_cast<const float4*>(&Xl[(rg * 4 + r) * DIN + k]);
                    acc[r][0] = fmaf(x.x, w0.x, fmaf(x.y, w1.x, fmaf(x.z, w2.x, fmaf(x.w, w3.x, acc[r][0]))));
                    acc[r][1] = fmaf(x.x, w0.y, fmaf(x.y, w1.y, fmaf(x.z, w2.y, fmaf(x.w, w3.y, acc[r][1]))));
                    acc[r][2] = fmaf(x.x, w0.z, fmaf(x.y, w1.z, fmaf(x.z, w2.z, fmaf(x.w, w3.z, acc[r][2]))));
                    acc[r][3] = fmaf(x.x, w0.w, fmaf(x.y, w1.w, fmaf(x.z, w2.w, fmaf(x.w, w3.w, acc[r][3]))));
                }
            }
            #pragma unroll
            for (int r = 0; r < 4; ++r) {
                long row = r0 + rg * 4 + r;
                if (row < N) {
                    float nm = norm[row];
                    float4 o;
                    o.x = acc[r][0] * nm; o.y = acc[r][1] * nm;
                    o.z = acc[r][2] * nm; o.w = acc[r][3] * nm;
                    *reinterpret_cast<float4*>(&z[row * DOUT + c0]) = o;
                }
            }
        }
    }
}

__global__ void final_kernel(float* __restrict__ out, const float* __restrict__ norm,
                             const float* __restrict__ b2, int N) {
    long total = (long)N * DOUT;
    long stride = (long)gridDim.x * blockDim.x;
    for (long i = (long)blockIdx.x * blockDim.x + threadIdx.x; i < total; i += stride) {
        int n = (int)(i / DOUT), d = (int)(i % DOUT);
        out[i] = fmaf(out[i], norm[n], b2[d]);
    }
}

// ---------------- launch ----------------

static inline size_t al4k(size_t x) { return (x + 4095) & ~(size_t)4095; }

extern "C" void kernel_launch(void* const* d_in, const int* in_sizes, int n_in,
                              void* d_out, int out_size, void* d_ws, size_t ws_size,
                              hipStream_t stream) {
    const float* feat = (const float*)d_in[0];
    const int*   src  = (const int*)d_in[1];
    const int*   dst  = (const int*)d_in[2];
    const float* W1   = (const float*)d_in[3];
    const float* b1   = (const float*)d_in[4];
    const float* W2   = (const float*)d_in[5];
    const float* b2   = (const float*)d_in[6];
    int N = in_sizes[0] / DIN;
    int E = in_sizes[1];
    float* out = (float*)d_out;
    char* ws = (char*)d_ws;

    int NB = (N + BNODES - 1) >> BSHIFT;
    int cap = ((E / (NB > 0 ? NB : 1)) * 5 / 4 + 256 + 1) & ~1;

    size_t o_norm   = 0;
    size_t o_rowptr = o_norm   + al4k((size_t)N * 4);
    size_t o_bcur   = o_rowptr + al4k(((size_t)N + 1) * 4);
    size_t o_perm   = o_bcur   + al4k((size_t)(NB + 1) * 4);
    size_t o_esrc   = o_perm   + al4k((size_t)N * 4);
    size_t o_aggh   = o_esrc   + al4k((size_t)E * 4);       // packed bucketbuf aliases aggh
    size_t o_y      = o_aggh   + al4k((size_t)N * DIN * 2);
    size_t o_z      = o_y      + al4k((size_t)N * DIN * 2);
    size_t o_w1f    = o_z      + al4k((size_t)N * DOUT * 2);
    size_t o_w2f    = o_w1f    + al4k((size_t)16384 * 2);
    size_t need     = o_w2f    + al4k((size_t)6144 * 2);

    bool bb_fits = (size_t)NB * cap * 4 <= (size_t)N * DIN * 2;
    bool packs   = N <= (1 << 22);

    if (ws_size >= need && NB <= 256 && bb_fits && packs) {
        float*  norm   = (float*)(ws + o_norm);
        int*    rowptr = (int*)(ws + o_rowptr);
        int*    bcur   = (int*)(ws + o_bcur);
        int*    perm   = (int*)(ws + o_perm);
        int*    esrc   = (int*)(ws + o_esrc);
        __half* aggh   = (__half*)(ws + o_aggh);
        int*    bbuf   = (int*)(ws + o_aggh);
        __half* y      = (__half*)(ws + o_y);
        __half* z      = (__half*)(ws + o_z);
        __half* w1f    = (__half*)(ws + o_w1f);
        __half* w2f    = (__half*)(ws + o_w2f);

        hipMemsetAsync(bcur, 0, (size_t)(NB + 1) * 4, stream);

        int p1grid = (E + 8191) / 8192;
        prep_pass1<<<p1grid + 11, 256, 0, stream>>>(W1, W2, w1f, w2f, src, dst, E, NB, cap, bcur, bbuf);
        pass2_sort<<<NB, 256, 0, stream>>>(bbuf, bcur, N, NB, cap, norm, rowptr, esrc);
        int npermblk = (N + 4095) / 4096;
        perm_yconv<<<npermblk + 2048, 256, 0, stream>>>(rowptr, perm, feat, norm, y, N, npermblk);

        gather1_kernel<<<(N * 16 + 255) / 256, 256, 0, stream>>>(y, rowptr, esrc, perm, norm, aggh, N);
        mmfused_kernel<<<512, 256, 0, stream>>>(aggh, w1f, w2f, b1, norm, z, N);
        gather2_kernel<<<(N + 47) / 48, 256, 0, stream>>>(z, rowptr, esrc, perm, norm, b2, out, N);
    } else {
        size_t f_norm = 0;
        size_t f_agg  = f_norm + al4k((size_t)N * 4);
        size_t f_z    = f_agg  + al4k((size_t)N * DIN * 4);
        float* norm = (float*)(ws + f_norm);
        float* agg  = (float*)(ws + f_agg);
        float* z    = (float*)(ws + f_z);
        int*   degi = (int*)(ws + f_norm);

        hipMemsetAsync(degi, 0, (size_t)N * 4, stream);
        hipMemsetAsync(agg, 0, (size_t)N * DIN * 4, stream);
        hipMemsetAsync(d_out, 0, (size_t)N * DOUT * 4, stream);

        degi_kernel<<<1024, 256, 0, stream>>>(dst, E, degi);
        norm_from_deg<<<(N + 255) / 256, 256, 0, stream>>>(degi, (float*)degi, N);
        scatter1_kernel<<<4096, 256, 0, stream>>>(feat, src, dst, norm, agg, E);
        mm1f_kernel<<<(N + 31) / 32, 256, 0, stream>>>(agg, W1, b1, norm, N);
        mm2f_kernel<<<(N + 63) / 64, 256, 0, stream>>>(agg, W2, norm, z, N);
        scatter2_kernel<<<4096, 256, 0, stream>>>(z, src, dst, out, E);
        final_kernel<<<4096, 256, 0, stream>>>(out, norm, b2, N);
    }
}

// Round 13
// 210.641 us; speedup vs baseline: 1.1538x; 1.1016x over previous
//
#include <hip/hip_runtime.h>
#include <hip/hip_fp16.h>
#include <math.h>

// SGC 2-layer: out = A_hat * elu(A_hat * X * W1 + b1) * W2 + b2
// A_hat = D^-1/2 A D^-1/2 (in-degree based, clip(deg,1))
// R2: CSR + gather. R4: counting-sort CSR. R5: fp16 operands. R6: wide loads +
// degree-perm. R7: MFMA fused matmul 308->239us. R11: chunk-4096 perm confirmed
// causal for gather1 62us. R12: launch consolidation 243->232us.
// R13: fuse matmul INTO gather1 (gather1mm): 16 perm-consecutive nodes/block,
//      rows staged in swizzled LDS (no aggh global round-trip, 51MB saved),
//      W frags read from global (L1-hot) to protect occupancy; pass1 CHUNK
//      8192->2048 (196->782 blocks, better LDS-atomic latency hiding).

#define DIN  128
#define DHID 128
#define DOUT 40
#define BSHIFT 9
#define BNODES 512   // 1 << BSHIFT

union U8  { uint2 u; __half2 h[2]; };
union U16 { uint4 u; __half2 h[4]; };

typedef _Float16     f16x8 __attribute__((ext_vector_type(8)));
typedef float        f32x4 __attribute__((ext_vector_type(4)));
union F16X8 { uint4 u; f16x8 f; };
union HCV   { __half h; unsigned short s; };
union FV4   { float4 h; f32x4 v; };

__device__ __forceinline__ float elu_f(float x) {
    return x > 0.0f ? x : (expf(x) - 1.0f);
}

// ---------------- merged wprep + pass1 (bucket edges by dst>>9) ----------------
__global__ void prep_pass1(const float* __restrict__ W1, const float* __restrict__ W2,
                           __half* __restrict__ w1f, __half* __restrict__ w2f,
                           const int* __restrict__ src, const int* __restrict__ dst,
                           int E, int NB, int cap,
                           int* __restrict__ bcur, int* __restrict__ bbuf) {
    __shared__ int cnt[256];
    __shared__ int wcur[256];
    if (blockIdx.x < 11) {
        int tid = blockIdx.x * 256 + threadIdx.x;
        if (tid < 2048) {
            int l = tid & 63;
            int t = (tid >> 6) & 3;
            int c = tid >> 8;
            int kb = t * 32 + (l >> 4) * 8, col = c * 16 + (l & 15);
            #pragma unroll
            for (int j = 0; j < 8; ++j)
                w1f[tid * 8 + j] = __float2half_rn(W1[(kb + j) * DHID + col]);
        } else if (tid < 2048 + 768) {
            int id = tid - 2048;
            int l = id & 63;
            int t = (id >> 6) & 3;
            int c = id >> 8;
            int kb = t * 32 + (l >> 4) * 8, col = c * 16 + (l & 15);
            #pragma unroll
            for (int j = 0; j < 8; ++j)
                w2f[id * 8 + j] = (col < DOUT) ? __float2half_rn(W2[(kb + j) * DOUT + col])
                                               : __float2half_rn(0.f);
        }
        return;
    }
    int bid = blockIdx.x - 11;
    int nblk = gridDim.x - 11;
    const int CHUNK = 2048;
    for (long base = (long)bid * CHUNK; base < E; base += (long)nblk * CHUNK) {
        int n = min(CHUNK, (int)(E - base));
        if (threadIdx.x < 256) cnt[threadIdx.x] = 0;
        __syncthreads();
        for (int i = threadIdx.x; i < n; i += blockDim.x) {
            int b = dst[base + i] >> BSHIFT;
            atomicAdd(&cnt[b], 1);
        }
        __syncthreads();
        if (threadIdx.x < NB) {
            int c = cnt[threadIdx.x];
            wcur[threadIdx.x] = (c > 0) ? atomicAdd(&bcur[threadIdx.x], c) : 0;
        }
        __syncthreads();
        for (int i = threadIdx.x; i < n; i += blockDim.x) {
            int s = src[base + i];
            int d = dst[base + i];
            int b = d >> BSHIFT;
            int slot = atomicAdd(&wcur[b], 1);
            if (slot < cap) bbuf[(long)b * cap + slot] = (s << BSHIFT) | (d & (BNODES - 1));
        }
        __syncthreads();
    }
}

// per-bucket LDS counting sort -> norm, rowptr, esrc; bucket base via in-block scan.
__global__ void pass2_sort(const int* __restrict__ bbuf, const int* __restrict__ bcur,
                           int N, int NB, int cap,
                           float* __restrict__ norm, int* __restrict__ rowptr,
                           int* __restrict__ esrc) {
    __shared__ int cnt[BNODES];
    __shared__ int scnt[256];
    __shared__ int sgbase;
    int tid = threadIdx.x;
    int b = blockIdx.x;
    scnt[tid] = (tid < NB) ? bcur[tid] : 0;
    __syncthreads();
    if (tid == 0) {
        int run = 0;
        for (int i = 0; i < NB; ++i) { if (i == b) sgbase = run; run += scnt[i]; }
        if (b == NB - 1) rowptr[N] = run;
    }
    __syncthreads();
    int gbase = sgbase;
    int n_b = min(bcur[b], cap);
    int dbase = b << BSHIFT;
    const int* eb = bbuf + (long)b * cap;
    for (int i = tid; i < BNODES; i += blockDim.x) cnt[i] = 0;
    __syncthreads();
    for (int i = tid; i < n_b; i += blockDim.x)
        atomicAdd(&cnt[eb[i] & (BNODES - 1)], 1);
    __syncthreads();
    for (int i = tid; i < BNODES; i += blockDim.x) {
        int d = dbase + i;
        if (d < N) norm[d] = rsqrtf(fmaxf((float)cnt[i], 1.0f));
    }
    __syncthreads();
    if (tid == 0) {
        int run = 0;
        #pragma unroll 4
        for (int i = 0; i < BNODES; ++i) { int c = cnt[i]; cnt[i] = run; run += c; }
    }
    __syncthreads();
    for (int i = tid; i < BNODES; i += blockDim.x) {
        int d = dbase + i;
        if (d < N) rowptr[d] = gbase + cnt[i];
    }
    __syncthreads();
    for (int i = tid; i < n_b; i += blockDim.x) {
        int v = eb[i];
        int slot = atomicAdd(&cnt[v & (BNODES - 1)], 1);
        esrc[gbase + slot] = ((unsigned)v) >> BSHIFT;
    }
}

// ---------------- merged perm_build + yconv ----------------
__global__ void perm_yconv(const int* __restrict__ rowptr, int* __restrict__ perm,
                           const float* __restrict__ feat, const float* __restrict__ norm,
                           __half* __restrict__ y, int N, int npermblk) {
    __shared__ int lcnt[1024];
    __shared__ int lbase[1024];
    if ((int)blockIdx.x < npermblk) {
        const int CHUNK = 4096;
        for (long base = (long)blockIdx.x * CHUNK; base < N; base += (long)npermblk * CHUNK) {
            int n = min(CHUNK, (int)(N - base));
            for (int i = threadIdx.x; i < 1024; i += 256) lcnt[i] = 0;
            __syncthreads();
            for (int i = threadIdx.x; i < n; i += 256) {
                int d = min(rowptr[base + i + 1] - rowptr[base + i], 1023);
                atomicAdd(&lcnt[d], 1);
            }
            __syncthreads();
            if (threadIdx.x == 0) {
                int run = 0;
                for (int i = 0; i < 1024; ++i) { int c = lcnt[i]; lbase[i] = run; run += c; }
            }
            __syncthreads();
            for (int i = threadIdx.x; i < 1024; i += 256) lcnt[i] = 0;
            __syncthreads();
            for (int i = threadIdx.x; i < n; i += 256) {
                int d = min(rowptr[base + i + 1] - rowptr[base + i], 1023);
                int pos = lbase[d] + atomicAdd(&lcnt[d], 1);
                perm[base + pos] = base + (int)i;
            }
            __syncthreads();
        }
        return;
    }
    long total = (long)N * 32;
    long stride = (long)(gridDim.x - npermblk) * 256;
    const float4* f4 = reinterpret_cast<const float4*>(feat);
    uint2* y2 = reinterpret_cast<uint2*>(y);
    for (long i = (long)(blockIdx.x - npermblk) * 256 + threadIdx.x; i < total; i += stride) {
        int n = (int)(i >> 5);
        float nm = norm[n];
        float4 v = f4[i];
        U8 o;
        o.h[0] = __floats2half2_rn(v.x * nm, v.y * nm);
        o.h[1] = __floats2half2_rn(v.z * nm, v.w * nm);
        y2[i] = o.u;
    }
}

__global__ void norm_from_deg(const int* __restrict__ deg, float* __restrict__ norm, int N) {
    int stride = gridDim.x * blockDim.x;
    for (int i = blockIdx.x * blockDim.x + threadIdx.x; i < N; i += stride)
        norm[i] = rsqrtf(fmaxf((float)deg[i], 1.0f));
}

__global__ void degi_kernel(const int* __restrict__ dst, int E, int* __restrict__ deg) {
    int stride = gridDim.x * blockDim.x;
    for (int i = blockIdx.x * blockDim.x + threadIdx.x; i < E; i += stride)
        atomicAdd(&deg[dst[i]], 1);
}

// ---------------- fused gather1 + matmul ----------------
// Block = 16 perm-consecutive nodes (near-equal degree). Each 16-lane group
// gathers one node's 128-d fp16 row (dst-norm folded), stages it in swizzled
// LDS, then the block's 4 waves run mm1 (2 col-tiles each) + mm2 (waves 0-2)
// with W fragments streamed from the global fragment table (L1-hot).
// z[n] = fp16(norm * elu(row @ W1 + b1) @ W2). Numerics identical to
// gather1(aggh)+mmfused (same fp16 rounding points).
__launch_bounds__(256, 5)
__global__ void gather1mm_kernel(const __half* __restrict__ y, const int* __restrict__ rowptr,
                                 const int* __restrict__ esrc, const int* __restrict__ perm,
                                 const float* __restrict__ norm,
                                 const __half* __restrict__ w1f, const __half* __restrict__ w2f,
                                 const float* __restrict__ b1, __half* __restrict__ z, int N) {
    __shared__ unsigned short Xt[16 * 128];   // 4KB, XOR-swizzled
    __shared__ unsigned short Ht[16 * 128];   // 4KB, XOR-swizzled
    __shared__ int   tN[16];
    __shared__ float tNm[16];
    int tid = threadIdx.x;
    int g = tid >> 4, l16 = tid & 15;

    long gi = (long)blockIdx.x * 16 + g;
    int n = -1, beg = 0, end = 0;
    float nm = 0.f;
    if (gi < N) { n = perm[gi]; beg = rowptr[n]; end = rowptr[n + 1]; nm = norm[n]; }

    float a0 = 0.f, a1 = 0.f, a2 = 0.f, a3 = 0.f;
    float a4f = 0.f, a5 = 0.f, a6 = 0.f, a7 = 0.f;
    const uint4* y4 = reinterpret_cast<const uint4*>(y);
    int j = beg;
    for (; j + 1 < end; j += 2) {
        int s0 = esrc[j], s1 = esrc[j + 1];
        U16 u0, u1;
        u0.u = y4[(long)s0 * 16 + l16];
        u1.u = y4[(long)s1 * 16 + l16];
        float2 p0 = __half22float2(u0.h[0]), p1 = __half22float2(u0.h[1]);
        float2 p2 = __half22float2(u0.h[2]), p3 = __half22float2(u0.h[3]);
        float2 q0 = __half22float2(u1.h[0]), q1 = __half22float2(u1.h[1]);
        float2 q2 = __half22float2(u1.h[2]), q3 = __half22float2(u1.h[3]);
        a0 += p0.x + q0.x; a1 += p0.y + q0.y;
        a2 += p1.x + q1.x; a3 += p1.y + q1.y;
        a4f += p2.x + q2.x; a5 += p2.y + q2.y;
        a6 += p3.x + q3.x; a7 += p3.y + q3.y;
    }
    if (j < end) {
        int s0 = esrc[j];
        U16 u0; u0.u = y4[(long)s0 * 16 + l16];
        float2 p0 = __half22float2(u0.h[0]), p1 = __half22float2(u0.h[1]);
        float2 p2 = __half22float2(u0.h[2]), p3 = __half22float2(u0.h[3]);
        a0 += p0.x; a1 += p0.y; a2 += p1.x; a3 += p1.y;
        a4f += p2.x; a5 += p2.y; a6 += p3.x; a7 += p3.y;
    }
    U16 o;
    o.h[0] = __floats2half2_rn(a0 * nm, a1 * nm);
    o.h[1] = __floats2half2_rn(a2 * nm, a3 * nm);
    o.h[2] = __floats2half2_rn(a4f * nm, a5 * nm);
    o.h[3] = __floats2half2_rn(a6 * nm, a7 * nm);
    {
        int ba = (g * 256 + l16 * 16) ^ ((g & 7) << 4);
        *reinterpret_cast<uint4*>(reinterpret_cast<char*>(Xt) + ba) = o.u;
    }
    if (l16 == 0) { tN[g] = n; tNm[g] = nm; }
    __syncthreads();

    // ---- mm1: 16 rows x 128, each wave does 2 col-tiles ----
    int w = tid >> 6, l = tid & 63;
    int lr = l & 15, lg = l >> 4;
    F16X8 af[4];
    #pragma unroll
    for (int t = 0; t < 4; ++t) {
        int ba = (lr * 256 + (t * 32 + lg * 8) * 2) ^ ((lr & 7) << 4);
        af[t].u = *reinterpret_cast<const uint4*>(reinterpret_cast<const char*>(Xt) + ba);
    }
    const uint4* w1g = reinterpret_cast<const uint4*>(w1f);
    const uint4* w2g = reinterpret_cast<const uint4*>(w2f);
    #pragma unroll
    for (int cc = 0; cc < 2; ++cc) {
        int c = w * 2 + cc;
        float bb = b1[c * 16 + lr];
        f32x4 acc = {bb, bb, bb, bb};
        #pragma unroll
        for (int t = 0; t < 4; ++t) {
            F16X8 bf; bf.u = w1g[(c * 4 + t) * 64 + l];
            acc = __builtin_amdgcn_mfma_f32_16x16x32_f16(af[t].f, bf.f, acc, 0, 0, 0);
        }
        int colb2 = (c * 16 + lr) * 2;
        #pragma unroll
        for (int i = 0; i < 4; ++i) {
            int rl = lg * 4 + i;
            HCV cv; cv.h = __float2half_rn(elu_f(acc[i]));
            int ba = (rl * 256 + colb2) ^ ((rl & 7) << 4);
            *reinterpret_cast<unsigned short*>(reinterpret_cast<char*>(Ht) + ba) = cv.s;
        }
    }
    __syncthreads();

    // ---- mm2: waves 0-2, one col-tile each ----
    if (w < 3) {
        F16X8 hf[4];
        #pragma unroll
        for (int t = 0; t < 4; ++t) {
            int ba = (lr * 256 + (t * 32 + lg * 8) * 2) ^ ((lr & 7) << 4);
            hf[t].u = *reinterpret_cast<const uint4*>(reinterpret_cast<const char*>(Ht) + ba);
        }
        f32x4 acc = {0.f, 0.f, 0.f, 0.f};
        #pragma unroll
        for (int t = 0; t < 4; ++t) {
            F16X8 bf; bf.u = w2g[(w * 4 + t) * 64 + l];
            acc = __builtin_amdgcn_mfma_f32_16x16x32_f16(hf[t].f, bf.f, acc, 0, 0, 0);
        }
        int col = w * 16 + lr;
        if (col < DOUT) {
            #pragma unroll
            for (int i = 0; i < 4; ++i) {
                int rl = lg * 4 + i;
                int nn = tN[rl];
                if (nn >= 0)
                    z[(long)nn * DOUT + col] = __float2half_rn(acc[i] * tNm[rl]);
            }
        }
    }
}

// out[n] = norm[n] * sum_j z[esrc[j]] + b2 ; 12 nodes/wave, 5 lanes x uint4 per node.
__global__ void gather2_kernel(const __half* __restrict__ z, const int* __restrict__ rowptr,
                               const int* __restrict__ esrc, const int* __restrict__ perm,
                               const float* __restrict__ norm, const float* __restrict__ b2,
                               float* __restrict__ out, int N) {
    int lane = threadIdx.x & 63;
    int grp = lane / 5;
    int seg = lane - grp * 5;
    bool act = grp < 12;
    long wglob = ((long)blockIdx.x * blockDim.x + threadIdx.x) >> 6;
    long g0 = wglob * 12 + grp;
    long gstride = (((long)gridDim.x * blockDim.x) >> 6) * 12;
    const uint4* z4 = reinterpret_cast<const uint4*>(z);
    for (long gi = g0; gi < N; gi += gstride) {
        if (act) {
            int n = perm[gi];
            int beg = rowptr[n], end = rowptr[n + 1];
            float a0 = 0.f, a1 = 0.f, a2 = 0.f, a3 = 0.f;
            float a4f = 0.f, a5 = 0.f, a6 = 0.f, a7 = 0.f;
            int j = beg;
            for (; j + 1 < end; j += 2) {
                int s0 = esrc[j], s1 = esrc[j + 1];
                U16 u0, u1;
                u0.u = z4[(long)s0 * 5 + seg];
                u1.u = z4[(long)s1 * 5 + seg];
                float2 p0 = __half22float2(u0.h[0]), p1 = __half22float2(u0.h[1]);
                float2 p2 = __half22float2(u0.h[2]), p3 = __half22float2(u0.h[3]);
                float2 q0 = __half22float2(u1.h[0]), q1 = __half22float2(u1.h[1]);
                float2 q2 = __half22float2(u1.h[2]), q3 = __half22float2(u1.h[3]);
                a0 += p0.x + q0.x; a1 += p0.y + q0.y;
                a2 += p1.x + q1.x; a3 += p1.y + q1.y;
                a4f += p2.x + q2.x; a5 += p2.y + q2.y;
                a6 += p3.x + q3.x; a7 += p3.y + q3.y;
            }
            if (j < end) {
                int s0 = esrc[j];
                U16 u0; u0.u = z4[(long)s0 * 5 + seg];
                float2 p0 = __half22float2(u0.h[0]), p1 = __half22float2(u0.h[1]);
                float2 p2 = __half22float2(u0.h[2]), p3 = __half22float2(u0.h[3]);
                a0 += p0.x; a1 += p0.y; a2 += p1.x; a3 += p1.y;
                a4f += p2.x; a5 += p2.y; a6 += p3.x; a7 += p3.y;
            }
            float nm = norm[n];
            const float4* b4 = reinterpret_cast<const float4*>(b2);
            float4 bb0 = b4[seg * 2], bb1 = b4[seg * 2 + 1];
            FV4 o0, o1;
            o0.h.x = fmaf(a0, nm, bb0.x); o0.h.y = fmaf(a1, nm, bb0.y);
            o0.h.z = fmaf(a2, nm, bb0.z); o0.h.w = fmaf(a3, nm, bb0.w);
            o1.h.x = fmaf(a4f, nm, bb1.x); o1.h.y = fmaf(a5, nm, bb1.y);
            o1.h.z = fmaf(a6, nm, bb1.z); o1.h.w = fmaf(a7, nm, bb1.w);
            f32x4* out4 = reinterpret_cast<f32x4*>(out);
            __builtin_nontemporal_store(o0.v, &out4[(long)n * 10 + seg * 2]);
            __builtin_nontemporal_store(o1.v, &out4[(long)n * 10 + seg * 2 + 1]);
        }
    }
}

// ---------------- fallback (f32 atomic path) ----------------

__global__ void scatter1_kernel(const float* __restrict__ feat, const int* __restrict__ src,
                                const int* __restrict__ dst, const float* __restrict__ norm,
                                float* __restrict__ agg, int E) {
    long T = (long)blockIdx.x * blockDim.x + threadIdx.x;
    int l4 = (int)(T & 31);
    long e = T >> 5;
    long estride = ((long)gridDim.x * blockDim.x) >> 5;
    for (; e < E; e += estride) {
        int s = src[e], d = dst[e];
        float ns = norm[s];
        float4 v = reinterpret_cast<const float4*>(feat)[(long)s * 32 + l4];
        float* o = agg + (long)d * DIN + l4 * 4;
        atomicAdd(o + 0, v.x * ns);
        atomicAdd(o + 1, v.y * ns);
        atomicAdd(o + 2, v.z * ns);
        atomicAdd(o + 3, v.w * ns);
    }
}

__global__ void scatter2_kernel(const float* __restrict__ z, const int* __restrict__ src,
                                const int* __restrict__ dst, float* __restrict__ out, int E) {
    long T = (long)blockIdx.x * blockDim.x + threadIdx.x;
    int l = (int)(T & 15);
    long e = T >> 4;
    long estride = ((long)gridDim.x * blockDim.x) >> 4;
    for (; e < E; e += estride) {
        if (l < 10) {
            int s = src[e], d = dst[e];
            float4 v = reinterpret_cast<const float4*>(z)[(long)s * 10 + l];
            float* o = out + (long)d * DOUT + l * 4;
            atomicAdd(o + 0, v.x);
            atomicAdd(o + 1, v.y);
            atomicAdd(o + 2, v.z);
            atomicAdd(o + 3, v.w);
        }
    }
}

__launch_bounds__(256, 2)
__global__ void mm1f_kernel(float* __restrict__ xh, const float* __restrict__ W1,
                            const float* __restrict__ b1, const float* __restrict__ norm,
                            int N) {
    __shared__ float Wl[DIN * DHID];
    __shared__ float Xl[32 * DIN];
    for (int i = threadIdx.x; i < DIN * DHID; i += 256) Wl[i] = W1[i];
    int cg = threadIdx.x & 31;
    int rg = threadIdx.x >> 5;
    int c0 = cg * 4;
    for (long r0 = (long)blockIdx.x * 32; r0 < N; r0 += (long)gridDim.x * 32) {
        __syncthreads();
        for (int i = threadIdx.x; i < 32 * 32; i += 256) {
            int rr = i >> 5;
            long row = r0 + rr;
            float4 v = make_float4(0.f, 0.f, 0.f, 0.f);
            if (row < N) {
                v = reinterpret_cast<const float4*>(xh)[row * 32 + (i & 31)];
                float nm = norm[row];
                v.x *= nm; v.y *= nm; v.z *= nm; v.w *= nm;
            }
            reinterpret_cast<float4*>(Xl)[i] = v;
        }
        __syncthreads();
        float acc[4][4];
        float bx = b1[c0], by = b1[c0 + 1], bz = b1[c0 + 2], bw = b1[c0 + 3];
        #pragma unroll
        for (int r = 0; r < 4; ++r) { acc[r][0] = bx; acc[r][1] = by; acc[r][2] = bz; acc[r][3] = bw; }
        for (int k = 0; k < DIN; k += 4) {
            float4 w0 = *reinterpret_cast<const float4*>(&Wl[(k + 0) * DHID + c0]);
            float4 w1 = *reinterpret_cast<const float4*>(&Wl[(k + 1) * DHID + c0]);
            float4 w2 = *reinterpret_cast<const float4*>(&Wl[(k + 2) * DHID + c0]);
            float4 w3 = *reinterpret_cast<const float4*>(&Wl[(k + 3) * DHID + c0]);
            #pragma unroll
            for (int r = 0; r < 4; ++r) {
                float4 x = *reinterpret_cast<const float4*>(&Xl[(rg * 4 + r) * DIN + k]);
                acc[r][0] = fmaf(x.x, w0.x, fmaf(x.y, w1.x, fmaf(x.z, w2.x, fmaf(x.w, w3.x, acc[r][0]))));
                acc[r][1] = fmaf(x.x, w0.y, fmaf(x.y, w1.y, fmaf(x.z, w2.y, fmaf(x.w, w3.y, acc[r][1]))));
                acc[r][2] = fmaf(x.x, w0.z, fmaf(x.y, w1.z, fmaf(x.z, w2.z, fmaf(x.w, w3.z, acc[r][2]))));
                acc[r][3] = fmaf(x.x, w0.w, fmaf(x.y, w1.w, fmaf(x.z, w2.w, fmaf(x.w, w3.w, acc[r][3]))));
            }
        }
        #pragma unroll
        for (int r = 0; r < 4; ++r) {
            long row = r0 + rg * 4 + r;
            if (row < N) {
                float4 o;
                o.x = elu_f(acc[r][0]); o.y = elu_f(acc[r][1]);
                o.z = elu_f(acc[r][2]); o.w = elu_f(acc[r][3]);
                *reinterpret_cast<float4*>(&xh[row * DIN + c0]) = o;
            }
        }
    }
}

__launch_bounds__(256, 2)
__global__ void mm2f_kernel(const float* __restrict__ h, const float* __restrict__ W2,
                            const float* __restrict__ norm, float* __restrict__ z, int N) {
    __shared__ float Wl[DHID * DOUT];
    __shared__ float Xl[64 * DIN];
    for (int i = threadIdx.x; i < DHID * DOUT; i += 256) Wl[i] = W2[i];
    int cg = threadIdx.x & 15;
    int rg = threadIdx.x >> 4;
    int c0 = cg * 4;
    for (long r0 = (long)blockIdx.x * 64; r0 < N; r0 += (long)gridDim.x * 64) {
        __syncthreads();
        for (int i = threadIdx.x; i < 64 * 32; i += 256) {
            int rr = i >> 5;
            long row = r0 + rr;
            float4 v = make_float4(0.f, 0.f, 0.f, 0.f);
            if (row < N) v = reinterpret_cast<const float4*>(h)[row * 32 + (i & 31)];
            reinterpret_cast<float4*>(Xl)[i] = v;
        }
        __syncthreads();
        if (c0 < DOUT) {
            float acc[4][4];
            #pragma unroll
            for (int r = 0; r < 4; ++r) { acc[r][0] = 0.f; acc[r][1] = 0.f; acc[r][2] = 0.f; acc[r][3] = 0.f; }
            for (int k = 0; k < DHID; k += 4) {
                float4 w0 = *reinterpret_cast<const float4*>(&Wl[(k + 0) * DOUT + c0]);
                float4 w1 = *reinterpret_cast<const float4*>(&Wl[(k + 1) * DOUT + c0]);
                float4 w2 = *reinterpret_cast<const float4*>(&Wl[(k + 2) * DOUT + c0]);
                float4 w3 = *reinterpret_cast<const float4*>(&Wl[(k + 3) * DOUT + c0]);
                #pragma unroll
                for (int r = 0; r < 4; ++r) {
                    float4 x = *reinterpret_cast<const float4*>(&Xl[(rg * 4 + r) * DIN + k]);
                    acc[r][0] = fmaf(x.x, w0.x, fmaf(x.y, w1.x, fmaf(x.z, w2.x, fmaf(x.w, w3.x, acc[r][0]))));
                    acc[r][1] = fmaf(x.x, w0.y, fmaf(x.y, w1.y, fmaf(x.z, w2.y, fmaf(x.w, w3.y, acc[r][1]))));
                    acc[r][2] = fmaf(x.x, w0.z, fmaf(x.y, w1.z, fmaf(x.z, w2.z, fmaf(x.w, w3.z, acc[r][2]))));
                    acc[r][3] = fmaf(x.x, w0.w, fmaf(x.y, w1.w, fmaf(x.z, w2.w, fmaf(x.w, w3.w, acc[r][3]))));
                }
            }
            #pragma unroll
            for (int r = 0; r < 4; ++r) {
                long row = r0 + rg * 4 + r;
                if (row < N) {
                    float nm = norm[row];
                    float4 o;
                    o.x = acc[r][0] * nm; o.y = acc[r][1] * nm;
                    o.z = acc[r][2] * nm; o.w = acc[r][3] * nm;
                    *reinterpret_cast<float4*>(&z[row * DOUT + c0]) = o;
                }
            }
        }
    }
}

__global__ void final_kernel(float* __restrict__ out, const float* __restrict__ norm,
                             const float* __restrict__ b2, int N) {
    long total = (long)N * DOUT;
    long stride = (long)gridDim.x * blockDim.x;
    for (long i = (long)blockIdx.x * blockDim.x + threadIdx.x; i < total; i += stride) {
        int n = (int)(i / DOUT), d = (int)(i % DOUT);
        out[i] = fmaf(out[i], norm[n], b2[d]);
    }
}

// ---------------- launch ----------------

static inline size_t al4k(size_t x) { return (x + 4095) & ~(size_t)4095; }

extern "C" void kernel_launch(void* const* d_in, const int* in_sizes, int n_in,
                              void* d_out, int out_size, void* d_ws, size_t ws_size,
                              hipStream_t stream) {
    const float* feat = (const float*)d_in[0];
    const int*   src  = (const int*)d_in[1];
    const int*   dst  = (const int*)d_in[2];
    const float* W1   = (const float*)d_in[3];
    const float* b1   = (const float*)d_in[4];
    const float* W2   = (const float*)d_in[5];
    const float* b2   = (const float*)d_in[6];
    int N = in_sizes[0] / DIN;
    int E = in_sizes[1];
    float* out = (float*)d_out;
    char* ws = (char*)d_ws;

    int NB = (N + BNODES - 1) >> BSHIFT;
    int cap = ((E / (NB > 0 ? NB : 1)) * 5 / 4 + 256 + 1) & ~1;

    size_t o_norm   = 0;
    size_t o_rowptr = o_norm   + al4k((size_t)N * 4);
    size_t o_bcur   = o_rowptr + al4k(((size_t)N + 1) * 4);
    size_t o_perm   = o_bcur   + al4k((size_t)(NB + 1) * 4);
    size_t o_esrc   = o_perm   + al4k((size_t)N * 4);
    size_t o_y      = o_esrc   + al4k((size_t)E * 4);       // packed bucketbuf aliases y
    size_t o_z      = o_y      + al4k((size_t)N * DIN * 2);
    size_t o_w1f    = o_z      + al4k((size_t)N * DOUT * 2);
    size_t o_w2f    = o_w1f    + al4k((size_t)16384 * 2);
    size_t need     = o_w2f    + al4k((size_t)6144 * 2);

    bool bb_fits = (size_t)NB * cap * 4 <= (size_t)N * DIN * 2;
    bool packs   = N <= (1 << 22);

    if (ws_size >= need && NB <= 256 && bb_fits && packs) {
        float*  norm   = (float*)(ws + o_norm);
        int*    rowptr = (int*)(ws + o_rowptr);
        int*    bcur   = (int*)(ws + o_bcur);
        int*    perm   = (int*)(ws + o_perm);
        int*    esrc   = (int*)(ws + o_esrc);
        __half* y      = (__half*)(ws + o_y);
        int*    bbuf   = (int*)(ws + o_y);
        __half* z      = (__half*)(ws + o_z);
        __half* w1f    = (__half*)(ws + o_w1f);
        __half* w2f    = (__half*)(ws + o_w2f);

        hipMemsetAsync(bcur, 0, (size_t)(NB + 1) * 4, stream);

        int p1grid = (E + 2047) / 2048;
        prep_pass1<<<p1grid + 11, 256, 0, stream>>>(W1, W2, w1f, w2f, src, dst, E, NB, cap, bcur, bbuf);
        pass2_sort<<<NB, 256, 0, stream>>>(bbuf, bcur, N, NB, cap, norm, rowptr, esrc);
        int npermblk = (N + 4095) / 4096;
        perm_yconv<<<npermblk + 2048, 256, 0, stream>>>(rowptr, perm, feat, norm, y, N, npermblk);

        gather1mm_kernel<<<(N + 15) / 16, 256, 0, stream>>>(y, rowptr, esrc, perm, norm,
                                                            w1f, w2f, b1, z, N);
        gather2_kernel<<<(N + 47) / 48, 256, 0, stream>>>(z, rowptr, esrc, perm, norm, b2, out, N);
    } else {
        size_t f_norm = 0;
        size_t f_agg  = f_norm + al4k((size_t)N * 4);
        size_t f_z    = f_agg  + al4k((size_t)N * DIN * 4);
        float* norm = (float*)(ws + f_norm);
        float* agg  = (float*)(ws + f_agg);
        float* z    = (float*)(ws + f_z);
        int*   degi = (int*)(ws + f_norm);

        hipMemsetAsync(degi, 0, (size_t)N * 4, stream);
        hipMemsetAsync(agg, 0, (size_t)N * DIN * 4, stream);
        hipMemsetAsync(d_out, 0, (size_t)N * DOUT * 4, stream);

        degi_kernel<<<1024, 256, 0, stream>>>(dst, E, degi);
        norm_from_deg<<<(N + 255) / 256, 256, 0, stream>>>(degi, (float*)degi, N);
        scatter1_kernel<<<4096, 256, 0, stream>>>(feat, src, dst, norm, agg, E);
        mm1f_kernel<<<(N + 31) / 32, 256, 0, stream>>>(agg, W1, b1, norm, N);
        mm2f_kernel<<<(N + 63) / 64, 256, 0, stream>>>(agg, W2, norm, z, N);
        scatter2_kernel<<<4096, 256, 0, stream>>>(z, src, dst, out, E);
        final_kernel<<<4096, 256, 0, stream>>>(out, norm, b2, N);
    }
}

// Round 14
// 206.761 us; speedup vs baseline: 1.1755x; 1.0188x over previous
//
#include <hip/hip_runtime.h>
#include <hip/hip_fp16.h>
#include <math.h>

// SGC 2-layer: out = A_hat * elu(A_hat * X * W1 + b1) * W2 + b2
// A_hat = D^-1/2 A D^-1/2 (in-degree based, clip(deg,1))
// R2: CSR + gather. R4: counting-sort CSR. R5: fp16 operands. R6: wide loads +
// degree-perm. R7: MFMA fused matmul 308->239us. R11: chunk-4096 perm causal.
// R12: launch consolidation 243->232us. R13: gather1+matmul fusion 232->210.6us
//      (gather1mm 63.5us at FETCH floor 185MB, MfmaUtil 2.7%).
// R14: gather1mm launch_bounds 5->8 blocks/CU (occupancy 68%->~90%, VGPR=32 has
//      headroom); gather2 unroll-4 (z is L2-resident -> latency-bound regime,
//      unlike gather1's fetch-bound regime where unroll-4 failed in R3).

#define DIN  128
#define DHID 128
#define DOUT 40
#define BSHIFT 9
#define BNODES 512   // 1 << BSHIFT

union U8  { uint2 u; __half2 h[2]; };
union U16 { uint4 u; __half2 h[4]; };

typedef _Float16     f16x8 __attribute__((ext_vector_type(8)));
typedef float        f32x4 __attribute__((ext_vector_type(4)));
union F16X8 { uint4 u; f16x8 f; };
union HCV   { __half h; unsigned short s; };
union FV4   { float4 h; f32x4 v; };

__device__ __forceinline__ float elu_f(float x) {
    return x > 0.0f ? x : (expf(x) - 1.0f);
}

// ---------------- merged wprep + pass1 (bucket edges by dst>>9) ----------------
__global__ void prep_pass1(const float* __restrict__ W1, const float* __restrict__ W2,
                           __half* __restrict__ w1f, __half* __restrict__ w2f,
                           const int* __restrict__ src, const int* __restrict__ dst,
                           int E, int NB, int cap,
                           int* __restrict__ bcur, int* __restrict__ bbuf) {
    __shared__ int cnt[256];
    __shared__ int wcur[256];
    if (blockIdx.x < 11) {
        int tid = blockIdx.x * 256 + threadIdx.x;
        if (tid < 2048) {
            int l = tid & 63;
            int t = (tid >> 6) & 3;
            int c = tid >> 8;
            int kb = t * 32 + (l >> 4) * 8, col = c * 16 + (l & 15);
            #pragma unroll
            for (int j = 0; j < 8; ++j)
                w1f[tid * 8 + j] = __float2half_rn(W1[(kb + j) * DHID + col]);
        } else if (tid < 2048 + 768) {
            int id = tid - 2048;
            int l = id & 63;
            int t = (id >> 6) & 3;
            int c = id >> 8;
            int kb = t * 32 + (l >> 4) * 8, col = c * 16 + (l & 15);
            #pragma unroll
            for (int j = 0; j < 8; ++j)
                w2f[id * 8 + j] = (col < DOUT) ? __float2half_rn(W2[(kb + j) * DOUT + col])
                                               : __float2half_rn(0.f);
        }
        return;
    }
    int bid = blockIdx.x - 11;
    int nblk = gridDim.x - 11;
    const int CHUNK = 2048;
    for (long base = (long)bid * CHUNK; base < E; base += (long)nblk * CHUNK) {
        int n = min(CHUNK, (int)(E - base));
        if (threadIdx.x < 256) cnt[threadIdx.x] = 0;
        __syncthreads();
        for (int i = threadIdx.x; i < n; i += blockDim.x) {
            int b = dst[base + i] >> BSHIFT;
            atomicAdd(&cnt[b], 1);
        }
        __syncthreads();
        if (threadIdx.x < NB) {
            int c = cnt[threadIdx.x];
            wcur[threadIdx.x] = (c > 0) ? atomicAdd(&bcur[threadIdx.x], c) : 0;
        }
        __syncthreads();
        for (int i = threadIdx.x; i < n; i += blockDim.x) {
            int s = src[base + i];
            int d = dst[base + i];
            int b = d >> BSHIFT;
            int slot = atomicAdd(&wcur[b], 1);
            if (slot < cap) bbuf[(long)b * cap + slot] = (s << BSHIFT) | (d & (BNODES - 1));
        }
        __syncthreads();
    }
}

// per-bucket LDS counting sort -> norm, rowptr, esrc; bucket base via in-block scan.
__global__ void pass2_sort(const int* __restrict__ bbuf, const int* __restrict__ bcur,
                           int N, int NB, int cap,
                           float* __restrict__ norm, int* __restrict__ rowptr,
                           int* __restrict__ esrc) {
    __shared__ int cnt[BNODES];
    __shared__ int scnt[256];
    __shared__ int sgbase;
    int tid = threadIdx.x;
    int b = blockIdx.x;
    scnt[tid] = (tid < NB) ? bcur[tid] : 0;
    __syncthreads();
    if (tid == 0) {
        int run = 0;
        for (int i = 0; i < NB; ++i) { if (i == b) sgbase = run; run += scnt[i]; }
        if (b == NB - 1) rowptr[N] = run;
    }
    __syncthreads();
    int gbase = sgbase;
    int n_b = min(bcur[b], cap);
    int dbase = b << BSHIFT;
    const int* eb = bbuf + (long)b * cap;
    for (int i = tid; i < BNODES; i += blockDim.x) cnt[i] = 0;
    __syncthreads();
    for (int i = tid; i < n_b; i += blockDim.x)
        atomicAdd(&cnt[eb[i] & (BNODES - 1)], 1);
    __syncthreads();
    for (int i = tid; i < BNODES; i += blockDim.x) {
        int d = dbase + i;
        if (d < N) norm[d] = rsqrtf(fmaxf((float)cnt[i], 1.0f));
    }
    __syncthreads();
    if (tid == 0) {
        int run = 0;
        #pragma unroll 4
        for (int i = 0; i < BNODES; ++i) { int c = cnt[i]; cnt[i] = run; run += c; }
    }
    __syncthreads();
    for (int i = tid; i < BNODES; i += blockDim.x) {
        int d = dbase + i;
        if (d < N) rowptr[d] = gbase + cnt[i];
    }
    __syncthreads();
    for (int i = tid; i < n_b; i += blockDim.x) {
        int v = eb[i];
        int slot = atomicAdd(&cnt[v & (BNODES - 1)], 1);
        esrc[gbase + slot] = ((unsigned)v) >> BSHIFT;
    }
}

// ---------------- merged perm_build + yconv ----------------
__global__ void perm_yconv(const int* __restrict__ rowptr, int* __restrict__ perm,
                           const float* __restrict__ feat, const float* __restrict__ norm,
                           __half* __restrict__ y, int N, int npermblk) {
    __shared__ int lcnt[1024];
    __shared__ int lbase[1024];
    if ((int)blockIdx.x < npermblk) {
        const int CHUNK = 4096;
        for (long base = (long)blockIdx.x * CHUNK; base < N; base += (long)npermblk * CHUNK) {
            int n = min(CHUNK, (int)(N - base));
            for (int i = threadIdx.x; i < 1024; i += 256) lcnt[i] = 0;
            __syncthreads();
            for (int i = threadIdx.x; i < n; i += 256) {
                int d = min(rowptr[base + i + 1] - rowptr[base + i], 1023);
                atomicAdd(&lcnt[d], 1);
            }
            __syncthreads();
            if (threadIdx.x == 0) {
                int run = 0;
                for (int i = 0; i < 1024; ++i) { int c = lcnt[i]; lbase[i] = run; run += c; }
            }
            __syncthreads();
            for (int i = threadIdx.x; i < 1024; i += 256) lcnt[i] = 0;
            __syncthreads();
            for (int i = threadIdx.x; i < n; i += 256) {
                int d = min(rowptr[base + i + 1] - rowptr[base + i], 1023);
                int pos = lbase[d] + atomicAdd(&lcnt[d], 1);
                perm[base + pos] = base + (int)i;
            }
            __syncthreads();
        }
        return;
    }
    long total = (long)N * 32;
    long stride = (long)(gridDim.x - npermblk) * 256;
    const float4* f4 = reinterpret_cast<const float4*>(feat);
    uint2* y2 = reinterpret_cast<uint2*>(y);
    for (long i = (long)(blockIdx.x - npermblk) * 256 + threadIdx.x; i < total; i += stride) {
        int n = (int)(i >> 5);
        float nm = norm[n];
        float4 v = f4[i];
        U8 o;
        o.h[0] = __floats2half2_rn(v.x * nm, v.y * nm);
        o.h[1] = __floats2half2_rn(v.z * nm, v.w * nm);
        y2[i] = o.u;
    }
}

__global__ void norm_from_deg(const int* __restrict__ deg, float* __restrict__ norm, int N) {
    int stride = gridDim.x * blockDim.x;
    for (int i = blockIdx.x * blockDim.x + threadIdx.x; i < N; i += stride)
        norm[i] = rsqrtf(fmaxf((float)deg[i], 1.0f));
}

__global__ void degi_kernel(const int* __restrict__ dst, int E, int* __restrict__ deg) {
    int stride = gridDim.x * blockDim.x;
    for (int i = blockIdx.x * blockDim.x + threadIdx.x; i < E; i += stride)
        atomicAdd(&deg[dst[i]], 1);
}

// ---------------- fused gather1 + matmul ----------------
__launch_bounds__(256, 8)
__global__ void gather1mm_kernel(const __half* __restrict__ y, const int* __restrict__ rowptr,
                                 const int* __restrict__ esrc, const int* __restrict__ perm,
                                 const float* __restrict__ norm,
                                 const __half* __restrict__ w1f, const __half* __restrict__ w2f,
                                 const float* __restrict__ b1, __half* __restrict__ z, int N) {
    __shared__ unsigned short Xt[16 * 128];   // 4KB, XOR-swizzled
    __shared__ unsigned short Ht[16 * 128];   // 4KB, XOR-swizzled
    __shared__ int   tN[16];
    __shared__ float tNm[16];
    int tid = threadIdx.x;
    int g = tid >> 4, l16 = tid & 15;

    long gi = (long)blockIdx.x * 16 + g;
    int n = -1, beg = 0, end = 0;
    float nm = 0.f;
    if (gi < N) { n = perm[gi]; beg = rowptr[n]; end = rowptr[n + 1]; nm = norm[n]; }

    float a0 = 0.f, a1 = 0.f, a2 = 0.f, a3 = 0.f;
    float a4f = 0.f, a5 = 0.f, a6 = 0.f, a7 = 0.f;
    const uint4* y4 = reinterpret_cast<const uint4*>(y);
    int j = beg;
    for (; j + 1 < end; j += 2) {
        int s0 = esrc[j], s1 = esrc[j + 1];
        U16 u0, u1;
        u0.u = y4[(long)s0 * 16 + l16];
        u1.u = y4[(long)s1 * 16 + l16];
        float2 p0 = __half22float2(u0.h[0]), p1 = __half22float2(u0.h[1]);
        float2 p2 = __half22float2(u0.h[2]), p3 = __half22float2(u0.h[3]);
        float2 q0 = __half22float2(u1.h[0]), q1 = __half22float2(u1.h[1]);
        float2 q2 = __half22float2(u1.h[2]), q3 = __half22float2(u1.h[3]);
        a0 += p0.x + q0.x; a1 += p0.y + q0.y;
        a2 += p1.x + q1.x; a3 += p1.y + q1.y;
        a4f += p2.x + q2.x; a5 += p2.y + q2.y;
        a6 += p3.x + q3.x; a7 += p3.y + q3.y;
    }
    if (j < end) {
        int s0 = esrc[j];
        U16 u0; u0.u = y4[(long)s0 * 16 + l16];
        float2 p0 = __half22float2(u0.h[0]), p1 = __half22float2(u0.h[1]);
        float2 p2 = __half22float2(u0.h[2]), p3 = __half22float2(u0.h[3]);
        a0 += p0.x; a1 += p0.y; a2 += p1.x; a3 += p1.y;
        a4f += p2.x; a5 += p2.y; a6 += p3.x; a7 += p3.y;
    }
    U16 o;
    o.h[0] = __floats2half2_rn(a0 * nm, a1 * nm);
    o.h[1] = __floats2half2_rn(a2 * nm, a3 * nm);
    o.h[2] = __floats2half2_rn(a4f * nm, a5 * nm);
    o.h[3] = __floats2half2_rn(a6 * nm, a7 * nm);
    {
        int ba = (g * 256 + l16 * 16) ^ ((g & 7) << 4);
        *reinterpret_cast<uint4*>(reinterpret_cast<char*>(Xt) + ba) = o.u;
    }
    if (l16 == 0) { tN[g] = n; tNm[g] = nm; }
    __syncthreads();

    // ---- mm1: 16 rows x 128, each wave does 2 col-tiles ----
    int w = tid >> 6, l = tid & 63;
    int lr = l & 15, lg = l >> 4;
    F16X8 af[4];
    #pragma unroll
    for (int t = 0; t < 4; ++t) {
        int ba = (lr * 256 + (t * 32 + lg * 8) * 2) ^ ((lr & 7) << 4);
        af[t].u = *reinterpret_cast<const uint4*>(reinterpret_cast<const char*>(Xt) + ba);
    }
    const uint4* w1g = reinterpret_cast<const uint4*>(w1f);
    const uint4* w2g = reinterpret_cast<const uint4*>(w2f);
    #pragma unroll
    for (int cc = 0; cc < 2; ++cc) {
        int c = w * 2 + cc;
        float bb = b1[c * 16 + lr];
        f32x4 acc = {bb, bb, bb, bb};
        #pragma unroll
        for (int t = 0; t < 4; ++t) {
            F16X8 bf; bf.u = w1g[(c * 4 + t) * 64 + l];
            acc = __builtin_amdgcn_mfma_f32_16x16x32_f16(af[t].f, bf.f, acc, 0, 0, 0);
        }
        int colb2 = (c * 16 + lr) * 2;
        #pragma unroll
        for (int i = 0; i < 4; ++i) {
            int rl = lg * 4 + i;
            HCV cv; cv.h = __float2half_rn(elu_f(acc[i]));
            int ba = (rl * 256 + colb2) ^ ((rl & 7) << 4);
            *reinterpret_cast<unsigned short*>(reinterpret_cast<char*>(Ht) + ba) = cv.s;
        }
    }
    __syncthreads();

    // ---- mm2: waves 0-2, one col-tile each ----
    if (w < 3) {
        F16X8 hf[4];
        #pragma unroll
        for (int t = 0; t < 4; ++t) {
            int ba = (lr * 256 + (t * 32 + lg * 8) * 2) ^ ((lr & 7) << 4);
            hf[t].u = *reinterpret_cast<const uint4*>(reinterpret_cast<const char*>(Ht) + ba);
        }
        f32x4 acc = {0.f, 0.f, 0.f, 0.f};
        #pragma unroll
        for (int t = 0; t < 4; ++t) {
            F16X8 bf; bf.u = w2g[(w * 4 + t) * 64 + l];
            acc = __builtin_amdgcn_mfma_f32_16x16x32_f16(hf[t].f, bf.f, acc, 0, 0, 0);
        }
        int col = w * 16 + lr;
        if (col < DOUT) {
            #pragma unroll
            for (int i = 0; i < 4; ++i) {
                int rl = lg * 4 + i;
                int nn = tN[rl];
                if (nn >= 0)
                    z[(long)nn * DOUT + col] = __float2half_rn(acc[i] * tNm[rl]);
            }
        }
    }
}

// out[n] = norm[n] * sum_j z[esrc[j]] + b2 ; 12 nodes/wave, 5 lanes x uint4 per node.
// z is L2-resident (8MB) -> latency-bound; unroll-4 for MLP.
__global__ void gather2_kernel(const __half* __restrict__ z, const int* __restrict__ rowptr,
                               const int* __restrict__ esrc, const int* __restrict__ perm,
                               const float* __restrict__ norm, const float* __restrict__ b2,
                               float* __restrict__ out, int N) {
    int lane = threadIdx.x & 63;
    int grp = lane / 5;
    int seg = lane - grp * 5;
    bool act = grp < 12;
    long wglob = ((long)blockIdx.x * blockDim.x + threadIdx.x) >> 6;
    long g0 = wglob * 12 + grp;
    long gstride = (((long)gridDim.x * blockDim.x) >> 6) * 12;
    const uint4* z4 = reinterpret_cast<const uint4*>(z);
    for (long gi = g0; gi < N; gi += gstride) {
        if (act) {
            int n = perm[gi];
            int beg = rowptr[n], end = rowptr[n + 1];
            float a0 = 0.f, a1 = 0.f, a2 = 0.f, a3 = 0.f;
            float a4f = 0.f, a5 = 0.f, a6 = 0.f, a7 = 0.f;
            int j = beg;
            for (; j + 3 < end; j += 4) {
                int s0 = esrc[j], s1 = esrc[j + 1], s2 = esrc[j + 2], s3 = esrc[j + 3];
                U16 u0, u1, u2, u3;
                u0.u = z4[(long)s0 * 5 + seg];
                u1.u = z4[(long)s1 * 5 + seg];
                u2.u = z4[(long)s2 * 5 + seg];
                u3.u = z4[(long)s3 * 5 + seg];
                float2 p0 = __half22float2(u0.h[0]), p1 = __half22float2(u0.h[1]);
                float2 p2 = __half22float2(u0.h[2]), p3 = __half22float2(u0.h[3]);
                float2 q0 = __half22float2(u1.h[0]), q1 = __half22float2(u1.h[1]);
                float2 q2 = __half22float2(u1.h[2]), q3 = __half22float2(u1.h[3]);
                float2 r0 = __half22float2(u2.h[0]), r1 = __half22float2(u2.h[1]);
                float2 r2 = __half22float2(u2.h[2]), r3 = __half22float2(u2.h[3]);
                float2 t0 = __half22float2(u3.h[0]), t1 = __half22float2(u3.h[1]);
                float2 t2 = __half22float2(u3.h[2]), t3 = __half22float2(u3.h[3]);
                a0 += (p0.x + q0.x) + (r0.x + t0.x); a1 += (p0.y + q0.y) + (r0.y + t0.y);
                a2 += (p1.x + q1.x) + (r1.x + t1.x); a3 += (p1.y + q1.y) + (r1.y + t1.y);
                a4f += (p2.x + q2.x) + (r2.x + t2.x); a5 += (p2.y + q2.y) + (r2.y + t2.y);
                a6 += (p3.x + q3.x) + (r3.x + t3.x); a7 += (p3.y + q3.y) + (r3.y + t3.y);
            }
            for (; j < end; ++j) {
                int s0 = esrc[j];
                U16 u0; u0.u = z4[(long)s0 * 5 + seg];
                float2 p0 = __half22float2(u0.h[0]), p1 = __half22float2(u0.h[1]);
                float2 p2 = __half22float2(u0.h[2]), p3 = __half22float2(u0.h[3]);
                a0 += p0.x; a1 += p0.y; a2 += p1.x; a3 += p1.y;
                a4f += p2.x; a5 += p2.y; a6 += p3.x; a7 += p3.y;
            }
            float nm = norm[n];
            const float4* b4 = reinterpret_cast<const float4*>(b2);
            float4 bb0 = b4[seg * 2], bb1 = b4[seg * 2 + 1];
            FV4 o0, o1;
            o0.h.x = fmaf(a0, nm, bb0.x); o0.h.y = fmaf(a1, nm, bb0.y);
            o0.h.z = fmaf(a2, nm, bb0.z); o0.h.w = fmaf(a3, nm, bb0.w);
            o1.h.x = fmaf(a4f, nm, bb1.x); o1.h.y = fmaf(a5, nm, bb1.y);
            o1.h.z = fmaf(a6, nm, bb1.z); o1.h.w = fmaf(a7, nm, bb1.w);
            f32x4* out4 = reinterpret_cast<f32x4*>(out);
            __builtin_nontemporal_store(o0.v, &out4[(long)n * 10 + seg * 2]);
            __builtin_nontemporal_store(o1.v, &out4[(long)n * 10 + seg * 2 + 1]);
        }
    }
}

// ---------------- fallback (f32 atomic path) ----------------

__global__ void scatter1_kernel(const float* __restrict__ feat, const int* __restrict__ src,
                                const int* __restrict__ dst, const float* __restrict__ norm,
                                float* __restrict__ agg, int E) {
    long T = (long)blockIdx.x * blockDim.x + threadIdx.x;
    int l4 = (int)(T & 31);
    long e = T >> 5;
    long estride = ((long)gridDim.x * blockDim.x) >> 5;
    for (; e < E; e += estride) {
        int s = src[e], d = dst[e];
        float ns = norm[s];
        float4 v = reinterpret_cast<const float4*>(feat)[(long)s * 32 + l4];
        float* o = agg + (long)d * DIN + l4 * 4;
        atomicAdd(o + 0, v.x * ns);
        atomicAdd(o + 1, v.y * ns);
        atomicAdd(o + 2, v.z * ns);
        atomicAdd(o + 3, v.w * ns);
    }
}

__global__ void scatter2_kernel(const float* __restrict__ z, const int* __restrict__ src,
                                const int* __restrict__ dst, float* __restrict__ out, int E) {
    long T = (long)blockIdx.x * blockDim.x + threadIdx.x;
    int l = (int)(T & 15);
    long e = T >> 4;
    long estride = ((long)gridDim.x * blockDim.x) >> 4;
    for (; e < E; e += estride) {
        if (l < 10) {
            int s = src[e], d = dst[e];
            float4 v = reinterpret_cast<const float4*>(z)[(long)s * 10 + l];
            float* o = out + (long)d * DOUT + l * 4;
            atomicAdd(o + 0, v.x);
            atomicAdd(o + 1, v.y);
            atomicAdd(o + 2, v.z);
            atomicAdd(o + 3, v.w);
        }
    }
}

__launch_bounds__(256, 2)
__global__ void mm1f_kernel(float* __restrict__ xh, const float* __restrict__ W1,
                            const float* __restrict__ b1, const float* __restrict__ norm,
                            int N) {
    __shared__ float Wl[DIN * DHID];
    __shared__ float Xl[32 * DIN];
    for (int i = threadIdx.x; i < DIN * DHID; i += 256) Wl[i] = W1[i];
    int cg = threadIdx.x & 31;
    int rg = threadIdx.x >> 5;
    int c0 = cg * 4;
    for (long r0 = (long)blockIdx.x * 32; r0 < N; r0 += (long)gridDim.x * 32) {
        __syncthreads();
        for (int i = threadIdx.x; i < 32 * 32; i += 256) {
            int rr = i >> 5;
            long row = r0 + rr;
            float4 v = make_float4(0.f, 0.f, 0.f, 0.f);
            if (row < N) {
                v = reinterpret_cast<const float4*>(xh)[row * 32 + (i & 31)];
                float nm = norm[row];
                v.x *= nm; v.y *= nm; v.z *= nm; v.w *= nm;
            }
            reinterpret_cast<float4*>(Xl)[i] = v;
        }
        __syncthreads();
        float acc[4][4];
        float bx = b1[c0], by = b1[c0 + 1], bz = b1[c0 + 2], bw = b1[c0 + 3];
        #pragma unroll
        for (int r = 0; r < 4; ++r) { acc[r][0] = bx; acc[r][1] = by; acc[r][2] = bz; acc[r][3] = bw; }
        for (int k = 0; k < DIN; k += 4) {
            float4 w0 = *reinterpret_cast<const float4*>(&Wl[(k + 0) * DHID + c0]);
            float4 w1 = *reinterpret_cast<const float4*>(&Wl[(k + 1) * DHID + c0]);
            float4 w2 = *reinterpret_cast<const float4*>(&Wl[(k + 2) * DHID + c0]);
            float4 w3 = *reinterpret_cast<const float4*>(&Wl[(k + 3) * DHID + c0]);
            #pragma unroll
            for (int r = 0; r < 4; ++r) {
                float4 x = *reinterpret_cast<const float4*>(&Xl[(rg * 4 + r) * DIN + k]);
                acc[r][0] = fmaf(x.x, w0.x, fmaf(x.y, w1.x, fmaf(x.z, w2.x, fmaf(x.w, w3.x, acc[r][0]))));
                acc[r][1] = fmaf(x.x, w0.y, fmaf(x.y, w1.y, fmaf(x.z, w2.y, fmaf(x.w, w3.y, acc[r][1]))));
                acc[r][2] = fmaf(x.x, w0.z, fmaf(x.y, w1.z, fmaf(x.z, w2.z, fmaf(x.w, w3.z, acc[r][2]))));
                acc[r][3] = fmaf(x.x, w0.w, fmaf(x.y, w1.w, fmaf(x.z, w2.w, fmaf(x.w, w3.w, acc[r][3]))));
            }
        }
        #pragma unroll
        for (int r = 0; r < 4; ++r) {
            long row = r0 + rg * 4 + r;
            if (row < N) {
                float4 o;
                o.x = elu_f(acc[r][0]); o.y = elu_f(acc[r][1]);
                o.z = elu_f(acc[r][2]); o.w = elu_f(acc[r][3]);
                *reinterpret_cast<float4*>(&xh[row * DIN + c0]) = o;
            }
        }
    }
}

__launch_bounds__(256, 2)
__global__ void mm2f_kernel(const float* __restrict__ h, const float* __restrict__ W2,
                            const float* __restrict__ norm, float* __restrict__ z, int N) {
    __shared__ float Wl[DHID * DOUT];
    __shared__ float Xl[64 * DIN];
    for (int i = threadIdx.x; i < DHID * DOUT; i += 256) Wl[i] = W2[i];
    int cg = threadIdx.x & 15;
    int rg = threadIdx.x >> 4;
    int c0 = cg * 4;
    for (long r0 = (long)blockIdx.x * 64; r0 < N; r0 += (long)gridDim.x * 64) {
        __syncthreads();
        for (int i = threadIdx.x; i < 64 * 32; i += 256) {
            int rr = i >> 5;
            long row = r0 + rr;
            float4 v = make_float4(0.f, 0.f, 0.f, 0.f);
            if (row < N) v = reinterpret_cast<const float4*>(h)[row * 32 + (i & 31)];
            reinterpret_cast<float4*>(Xl)[i] = v;
        }
        __syncthreads();
        if (c0 < DOUT) {
            float acc[4][4];
            #pragma unroll
            for (int r = 0; r < 4; ++r) { acc[r][0] = 0.f; acc[r][1] = 0.f; acc[r][2] = 0.f; acc[r][3] = 0.f; }
            for (int k = 0; k < DHID; k += 4) {
                float4 w0 = *reinterpret_cast<const float4*>(&Wl[(k + 0) * DOUT + c0]);
                float4 w1 = *reinterpret_cast<const float4*>(&Wl[(k + 1) * DOUT + c0]);
                float4 w2 = *reinterpret_cast<const float4*>(&Wl[(k + 2) * DOUT + c0]);
                float4 w3 = *reinterpret_cast<const float4*>(&Wl[(k + 3) * DOUT + c0]);
                #pragma unroll
                for (int r = 0; r < 4; ++r) {
                    float4 x = *reinterpret_cast<const float4*>(&Xl[(rg * 4 + r) * DIN + k]);
                    acc[r][0] = fmaf(x.x, w0.x, fmaf(x.y, w1.x, fmaf(x.z, w2.x, fmaf(x.w, w3.x, acc[r][0]))));
                    acc[r][1] = fmaf(x.x, w0.y, fmaf(x.y, w1.y, fmaf(x.z, w2.y, fmaf(x.w, w3.y, acc[r][1]))));
                    acc[r][2] = fmaf(x.x, w0.z, fmaf(x.y, w1.z, fmaf(x.z, w2.z, fmaf(x.w, w3.z, acc[r][2]))));
                    acc[r][3] = fmaf(x.x, w0.w, fmaf(x.y, w1.w, fmaf(x.z, w2.w, fmaf(x.w, w3.w, acc[r][3]))));
                }
            }
            #pragma unroll
            for (int r = 0; r < 4; ++r) {
                long row = r0 + rg * 4 + r;
                if (row < N) {
                    float nm = norm[row];
                    float4 o;
                    o.x = acc[r][0] * nm; o.y = acc[r][1] * nm;
                    o.z = acc[r][2] * nm; o.w = acc[r][3] * nm;
                    *reinterpret_cast<float4*>(&z[row * DOUT + c0]) = o;
                }
            }
        }
    }
}

__global__ void final_kernel(float* __restrict__ out, const float* __restrict__ norm,
                             const float* __restrict__ b2, int N) {
    long total = (long)N * DOUT;
    long stride = (long)gridDim.x * blockDim.x;
    for (long i = (long)blockIdx.x * blockDim.x + threadIdx.x; i < total; i += stride) {
        int n = (int)(i / DOUT), d = (int)(i % DOUT);
        out[i] = fmaf(out[i], norm[n], b2[d]);
    }
}

// ---------------- launch ----------------

static inline size_t al4k(size_t x) { return (x + 4095) & ~(size_t)4095; }

extern "C" void kernel_launch(void* const* d_in, const int* in_sizes, int n_in,
                              void* d_out, int out_size, void* d_ws, size_t ws_size,
                              hipStream_t stream) {
    const float* feat = (const float*)d_in[0];
    const int*   src  = (const int*)d_in[1];
    const int*   dst  = (const int*)d_in[2];
    const float* W1   = (const float*)d_in[3];
    const float* b1   = (const float*)d_in[4];
    const float* W2   = (const float*)d_in[5];
    const float* b2   = (const float*)d_in[6];
    int N = in_sizes[0] / DIN;
    int E = in_sizes[1];
    float* out = (float*)d_out;
    char* ws = (char*)d_ws;

    int NB = (N + BNODES - 1) >> BSHIFT;
    int cap = ((E / (NB > 0 ? NB : 1)) * 5 / 4 + 256 + 1) & ~1;

    size_t o_norm   = 0;
    size_t o_rowptr = o_norm   + al4k((size_t)N * 4);
    size_t o_bcur   = o_rowptr + al4k(((size_t)N + 1) * 4);
    size_t o_perm   = o_bcur   + al4k((size_t)(NB + 1) * 4);
    size_t o_esrc   = o_perm   + al4k((size_t)N * 4);
    size_t o_y      = o_esrc   + al4k((size_t)E * 4);       // packed bucketbuf aliases y
    size_t o_z      = o_y      + al4k((size_t)N * DIN * 2);
    size_t o_w1f    = o_z      + al4k((size_t)N * DOUT * 2);
    size_t o_w2f    = o_w1f    + al4k((size_t)16384 * 2);
    size_t need     = o_w2f    + al4k((size_t)6144 * 2);

    bool bb_fits = (size_t)NB * cap * 4 <= (size_t)N * DIN * 2;
    bool packs   = N <= (1 << 22);

    if (ws_size >= need && NB <= 256 && bb_fits && packs) {
        float*  norm   = (float*)(ws + o_norm);
        int*    rowptr = (int*)(ws + o_rowptr);
        int*    bcur   = (int*)(ws + o_bcur);
        int*    perm   = (int*)(ws + o_perm);
        int*    esrc   = (int*)(ws + o_esrc);
        __half* y      = (__half*)(ws + o_y);
        int*    bbuf   = (int*)(ws + o_y);
        __half* z      = (__half*)(ws + o_z);
        __half* w1f    = (__half*)(ws + o_w1f);
        __half* w2f    = (__half*)(ws + o_w2f);

        hipMemsetAsync(bcur, 0, (size_t)(NB + 1) * 4, stream);

        int p1grid = (E + 2047) / 2048;
        prep_pass1<<<p1grid + 11, 256, 0, stream>>>(W1, W2, w1f, w2f, src, dst, E, NB, cap, bcur, bbuf);
        pass2_sort<<<NB, 256, 0, stream>>>(bbuf, bcur, N, NB, cap, norm, rowptr, esrc);
        int npermblk = (N + 4095) / 4096;
        perm_yconv<<<npermblk + 2048, 256, 0, stream>>>(rowptr, perm, feat, norm, y, N, npermblk);

        gather1mm_kernel<<<(N + 15) / 16, 256, 0, stream>>>(y, rowptr, esrc, perm, norm,
                                                            w1f, w2f, b1, z, N);
        gather2_kernel<<<(N + 47) / 48, 256, 0, stream>>>(z, rowptr, esrc, perm, norm, b2, out, N);
    } else {
        size_t f_norm = 0;
        size_t f_agg  = f_norm + al4k((size_t)N * 4);
        size_t f_z    = f_agg  + al4k((size_t)N * DIN * 4);
        float* norm = (float*)(ws + f_norm);
        float* agg  = (float*)(ws + f_agg);
        float* z    = (float*)(ws + f_z);
        int*   degi = (int*)(ws + f_norm);

        hipMemsetAsync(degi, 0, (size_t)N * 4, stream);
        hipMemsetAsync(agg, 0, (size_t)N * DIN * 4, stream);
        hipMemsetAsync(d_out, 0, (size_t)N * DOUT * 4, stream);

        degi_kernel<<<1024, 256, 0, stream>>>(dst, E, degi);
        norm_from_deg<<<(N + 255) / 256, 256, 0, stream>>>(degi, (float*)degi, N);
        scatter1_kernel<<<4096, 256, 0, stream>>>(feat, src, dst, norm, agg, E);
        mm1f_kernel<<<(N + 31) / 32, 256, 0, stream>>>(agg, W1, b1, norm, N);
        mm2f_kernel<<<(N + 63) / 64, 256, 0, stream>>>(agg, W2, norm, z, N);
        scatter2_kernel<<<4096, 256, 0, stream>>>(z, src, dst, out, E);
        final_kernel<<<4096, 256, 0, stream>>>(out, norm, b2, N);
    }
}